// Round 3
// baseline (2312.898 us; speedup 1.0000x reference)
//
#include <hip/hip_runtime.h>
#include <hip/hip_bf16.h>

#define NUM_RAYS 4096
#define S_PER 96
#define NPTS (NUM_RAYS * S_PER)
#define CCH 80
#define HID 64

// ws layout (float offsets)
#define WS_W1   0        // 15360 floats (3*80 x 64)
#define WS_W2   15360    // 256 floats (64 x 4)
#define WS_B1   15616    // 64
#define WS_B2   15680    // 4
#define WS_FLAG 16000    // int: 1 = inputs are bf16, 0 = inputs are float32

// d_out layout (elements of output dtype T):
// [0)      comp_rgb    3*4096  (c*4096 + ray)
// [12288)  comp_depth  4096
// [16384)  opacity     4096
// [20480)  comp_normal 3*4096
// [32768)  sdf_grad    393216*3  ((ray*96+s)*3 + c)

__device__ __forceinline__ float bf2f(__hip_bfloat16 v) { return __bfloat162float(v); }

template <bool BF16>
__device__ __forceinline__ float ldin(const void* p, size_t i) {
  if (BF16) return bf2f(((const __hip_bfloat16*)p)[i]);
  else      return ((const float*)p)[i];
}
template <bool BF16>
__device__ __forceinline__ void stout(void* p, size_t i, float v) {
  if (BF16) ((__hip_bfloat16*)p)[i] = __float2bfloat16(v);
  else      ((float*)p)[i] = v;
}

// Detect input dtype: interpret ray_directions as bf16; true bf16 data has
// per-ray norm == 1 (to bf16 rounding). float32 data misread as bf16 yields
// garbage exponents -> all-64-lanes-in-[0.95,1.05] is impossible.
__global__ void detect_kernel(const void* __restrict__ rdv, float* __restrict__ ws) {
  int lane = threadIdx.x;  // 64 threads
  const __hip_bfloat16* p = (const __hip_bfloat16*)rdv;
  float x = bf2f(p[lane * 3 + 0]);
  float y = bf2f(p[lane * 3 + 1]);
  float z = bf2f(p[lane * 3 + 2]);
  float n2 = x * x + y * y + z * z;
  bool ok = (n2 > 0.95f) && (n2 < 1.05f);   // NaN-safe: NaN compares false
  unsigned long long m = __ballot(ok);
  if (lane == 0) {
    *((int*)(ws + WS_FLAG)) = (m == ~0ull) ? 1 : 0;
  }
}

template <bool BF16>
__global__ void prep_kernel(const void* __restrict__ W1,
                            const void* __restrict__ b1,
                            const void* __restrict__ W2,
                            const void* __restrict__ b2,
                            float* __restrict__ ws) {
  if ((*((const int*)(ws + WS_FLAG)) != 0) != BF16) return;
  int tid = blockIdx.x * blockDim.x + threadIdx.x;
  if (tid < 15360) ws[WS_W1 + tid] = ldin<BF16>(W1, tid);
  if (tid < 256)   ws[WS_W2 + tid] = ldin<BF16>(W2, tid);
  if (tid < 64)    ws[WS_B1 + tid] = ldin<BF16>(b1, tid);
  if (tid < 4)     ws[WS_B2 + tid] = ldin<BF16>(b2, tid);
}

// One decode of a point: sample 3 planes x 80 ch, MLP 240->64(relu)->NOUT.
// Weight addresses are wave-uniform -> scalar loads; per-lane data in VGPRs.
template <bool BF16, int NOUT>
__device__ __forceinline__ void mlp_decode(const void* __restrict__ planes,
                                           const float* __restrict__ W1f,
                                           const float* __restrict__ b1f,
                                           const float* __restrict__ W2f,
                                           const float* __restrict__ b2v,
                                           float px, float py, float pz,
                                           float* o) {
  float h[HID];
  #pragma unroll
  for (int j = 0; j < HID; j++) h[j] = b1f[j];

  const float inv = 1.0f / 0.6f;
  float u3[3] = { px * inv, py * inv, pz * inv };

  #pragma unroll 1
  for (int p = 0; p < 3; p++) {
    // plane 0: (x,y); plane 1: (x,z); plane 2: (y,z)
    float u = (p == 2) ? u3[1] : u3[0];
    float v = (p == 0) ? u3[1] : u3[2];
    float fx = u * 32.0f + 31.5f;
    float fy = v * 32.0f + 31.5f;
    float flx = floorf(fx), fly = floorf(fy);
    int x0 = (int)flx, y0 = (int)fly;
    float wx = fx - flx, wy = fy - fly;
    int x1 = x0 + 1, y1 = y0 + 1;
    bool vx0 = (x0 >= 0) && (x0 < 64);
    bool vx1 = (x1 >= 0) && (x1 < 64);
    bool vy0 = (y0 >= 0) && (y0 < 64);
    bool vy1 = (y1 >= 0) && (y1 < 64);
    int cx0 = min(max(x0, 0), 63), cx1 = min(max(x1, 0), 63);
    int cy0 = min(max(y0, 0), 63), cy1 = min(max(y1, 0), 63);
    float w00 = (1.0f - wx) * (1.0f - wy) * ((vx0 && vy0) ? 1.0f : 0.0f);
    float w10 = wx * (1.0f - wy)          * ((vx1 && vy0) ? 1.0f : 0.0f);
    float w01 = (1.0f - wx) * wy          * ((vx0 && vy1) ? 1.0f : 0.0f);
    float w11 = wx * wy                   * ((vx1 && vy1) ? 1.0f : 0.0f);
    int o00 = cy0 * 64 + cx0, o10 = cy0 * 64 + cx1;
    int o01 = cy1 * 64 + cx0, o11 = cy1 * 64 + cx1;

    size_t pbase = (size_t)p * CCH * 4096;
    const float* wbase = W1f + p * CCH * HID;
    #pragma unroll 1
    for (int c = 0; c < CCH; c++) {
      size_t cb = pbase + (size_t)c * 4096;
      float f = w00 * ldin<BF16>(planes, cb + o00) + w10 * ldin<BF16>(planes, cb + o10)
              + w01 * ldin<BF16>(planes, cb + o01) + w11 * ldin<BF16>(planes, cb + o11);
      const float* wr = wbase + c * HID;   // wave-uniform address -> s_load
      #pragma unroll
      for (int j = 0; j < HID; j++) h[j] = fmaf(f, wr[j], h[j]);
    }
  }

  #pragma unroll
  for (int i = 0; i < NOUT; i++) o[i] = b2v[i];
  #pragma unroll
  for (int j = 0; j < HID; j++) {
    float hr = fmaxf(h[j], 0.0f);
    #pragma unroll
    for (int i = 0; i < NOUT; i++) o[i] = fmaf(hr, W2f[j * 4 + i], o[i]);
  }
}

#define RAYS_PER_BLOCK 2
#define BLOCK_T (RAYS_PER_BLOCK * S_PER)   // 192

template <bool BF16>
__global__ __launch_bounds__(BLOCK_T) void fused_kernel(
    const void* __restrict__ planes,
    const void* __restrict__ ro,
    const void* __restrict__ rd,
    const float* __restrict__ ws,
    void* __restrict__ out) {
  if ((*((const int*)(ws + WS_FLAG)) != 0) != BF16) return;

  __shared__ float rec[RAYS_PER_BLOCK][S_PER][8];

  int tid = threadIdx.x;
  int sidx = tid % S_PER;
  int rloc = tid / S_PER;
  int ray = blockIdx.x * RAYS_PER_BLOCK + rloc;
  int gid = ray * S_PER + sidx;

  // per-ray box intersection (recomputed per thread; trivial)
  float ox = ldin<BF16>(ro, ray*3+0), oy = ldin<BF16>(ro, ray*3+1), oz = ldin<BF16>(ro, ray*3+2);
  float dx = ldin<BF16>(rd, ray*3+0), dy = ldin<BF16>(rd, ray*3+1), dz = ldin<BF16>(rd, ray*3+2);
  float o3[3] = {ox, oy, oz}, d3[3] = {dx, dy, dz};
  float tmin = -1e30f, tmax = 1e30f;
  #pragma unroll
  for (int k = 0; k < 3; k++) {
    float sd = (fabsf(d3[k]) < 1e-9f) ? 1e-9f : d3[k];
    float ta = (-0.6f - o3[k]) / sd;
    float tb = ( 0.6f - o3[k]) / sd;
    tmin = fmaxf(tmin, fminf(ta, tb));
    tmax = fminf(tmax, fmaxf(ta, tb));
  }
  float tn = fmaxf(tmin, 0.0f);
  float span = fmaxf(tmax - tn, 0.0f);

  float frac = ((float)sidx + 0.5f) * (1.0f / (float)S_PER);
  float depth = tn + span * frac;
  float px = ox + depth * dx;
  float py = oy + depth * dy;
  float pz = oz + depth * dz;

  const float* W1f = ws + WS_W1;
  const float* W2f = ws + WS_W2;
  const float* b1f = ws + WS_B1;
  const float* b2v = ws + WS_B2;

  float o4[4];
  mlp_decode<BF16, 4>(planes, W1f, b1f, W2f, b2v, px, py, pz, o4);
  float sdf0 = o4[0];

  float g[3];
  #pragma unroll 1
  for (int i = 0; i < 3; i++) {
    float qx = px + ((i == 0) ? 0.01f : 0.0f);
    float qy = py + ((i == 1) ? 0.01f : 0.0f);
    float qz = pz + ((i == 2) ? 0.01f : 0.0f);
    qx = fminf(fmaxf(qx, -0.6f), 0.6f);
    qy = fminf(fmaxf(qy, -0.6f), 0.6f);
    qz = fminf(fmaxf(qz, -0.6f), 0.6f);
    float so[1];
    mlp_decode<BF16, 1>(planes, W1f, b1f, W2f, b2v, qx, qy, qz, so);
    g[i] = (so[0] - sdf0) * 100.0f;   // / EPS_FD
  }

  // sdf_grad output
  stout<BF16>(out, (size_t)32768 + (size_t)gid*3+0, g[0]);
  stout<BF16>(out, (size_t)32768 + (size_t)gid*3+1, g[1]);
  stout<BF16>(out, (size_t)32768 + (size_t)gid*3+2, g[2]);

  // rgb = sigmoid(o)*1.002 - 0.001
  float cr = 1.0f / (1.0f + expf(-o4[1])) * 1.002f - 0.001f;
  float cg = 1.0f / (1.0f + expf(-o4[2])) * 1.002f - 0.001f;
  float cb = 1.0f / (1.0f + expf(-o4[3])) * 1.002f - 0.001f;
  float pn = sqrtf(px*px + py*py + pz*pz);

  rec[rloc][sidx][0] = sdf0;
  rec[rloc][sidx][1] = cr;
  rec[rloc][sidx][2] = cg;
  rec[rloc][sidx][3] = cb;
  rec[rloc][sidx][4] = g[0];
  rec[rloc][sidx][5] = g[1];
  rec[rloc][sidx][6] = g[2];
  rec[rloc][sidx][7] = pn;

  __syncthreads();

  // one lane per ray composites serially
  if (sidx == 0) {
    float delta = span * (1.0f / (float)S_PER);
    float T = 1.0f, wsum = 0.0f, dep = 0.0f;
    float rgb[3] = {0.f, 0.f, 0.f};
    float nrm[3] = {0.f, 0.f, 0.f};

    #pragma unroll 1
    for (int s = 0; s < S_PER; s++) {
      float a0 = rec[rloc][s][0];
      float a1 = rec[rloc][s][1];
      float a2 = rec[rloc][s][2];
      float a3 = rec[rloc][s][3];
      float bx = rec[rloc][s][4];
      float by = rec[rloc][s][5];
      float bz = rec[rloc][s][6];
      float bw = rec[rloc][s][7];
      float dpt = tn + span * (((float)s + 0.5f) * (1.0f / (float)S_PER));
      float shifted = a0 + bw - 0.5f;
      float xarg = -shifted * 80.0f;
      float sigma = (xarg > 20.0f) ? xarg : log1pf(expf(xarg));
      float alpha = 1.0f - expf(-sigma * delta);
      float w = alpha * T;
      T = T * (1.0f - alpha + 1e-10f);
      wsum += w;
      dep += w * dpt;
      rgb[0] += w * a1; rgb[1] += w * a2; rgb[2] += w * a3;
      float gl = sqrtf(bx*bx + by*by + bz*bz) + 1e-8f;
      float igl = 1.0f / gl;
      nrm[0] += w * bx * igl; nrm[1] += w * by * igl; nrm[2] += w * bz * igl;
    }

    rgb[0] += 1.0f - wsum; rgb[1] += 1.0f - wsum; rgb[2] += 1.0f - wsum;
    float nl = sqrtf(nrm[0]*nrm[0] + nrm[1]*nrm[1] + nrm[2]*nrm[2]) + 1e-8f;
    float inl = 1.0f / nl;

    #pragma unroll
    for (int c = 0; c < 3; c++) {
      float n = (nrm[c] * inl + 1.0f) * 0.5f * wsum;
      stout<BF16>(out, (size_t)(c*4096 + ray), rgb[c]);
      stout<BF16>(out, (size_t)(20480 + c*4096 + ray), n);
    }
    stout<BF16>(out, (size_t)(12288 + ray), dep);
    stout<BF16>(out, (size_t)(16384 + ray), wsum);
  }
}

extern "C" void kernel_launch(void* const* d_in, const int* in_sizes, int n_in,
                              void* d_out, int out_size, void* d_ws, size_t ws_size,
                              hipStream_t stream) {
  const void* planes = d_in[0];
  const void* ro     = d_in[1];
  const void* rd     = d_in[2];
  const void* W1     = d_in[3];
  const void* b1     = d_in[4];
  const void* W2     = d_in[5];
  const void* b2     = d_in[6];
  float* ws = (float*)d_ws;

  detect_kernel<<<1, 64, 0, stream>>>(rd, ws);
  prep_kernel<false><<<60, 256, 0, stream>>>(W1, b1, W2, b2, ws);
  prep_kernel<true ><<<60, 256, 0, stream>>>(W1, b1, W2, b2, ws);
  fused_kernel<false><<<NUM_RAYS / RAYS_PER_BLOCK, BLOCK_T, 0, stream>>>(planes, ro, rd, ws, d_out);
  fused_kernel<true ><<<NUM_RAYS / RAYS_PER_BLOCK, BLOCK_T, 0, stream>>>(planes, ro, rd, ws, d_out);
}

// Round 4
// 1187.320 us; speedup vs baseline: 1.9480x; 1.9480x over previous
//
#include <hip/hip_runtime.h>
#include <hip/hip_bf16.h>

#define NUM_RAYS 4096
#define S_PER 96
#define NPTS (NUM_RAYS * S_PER)
#define CCH 80
#define HID 64

// ws layout (float offsets)
#define WS_W1   0        // 15360 floats (3*80 x 64) row-major [ch][64]
#define WS_W2   15360    // 256 floats (64 x 4)
#define WS_B1   15616    // 64
#define WS_B2   15680    // 4
#define WS_FLAG 16000    // int: 1 = inputs are bf16, 0 = inputs are float32
#define WS_PT   16384    // transposed planes: float [3][64][64][80] = 983040 floats
#define WS_NEEDED_BYTES ((size_t)(WS_PT + 3*64*64*80) * 4)

// d_out layout (elements of output dtype):
// [0) comp_rgb 3*4096 | [12288) depth 4096 | [16384) opacity 4096
// [20480) comp_normal 3*4096 | [32768) sdf_grad 393216*3

__device__ __forceinline__ float bf2f(__hip_bfloat16 v) { return __bfloat162float(v); }

template <bool BF16>
__device__ __forceinline__ float ldin(const void* p, size_t i) {
  if (BF16) return bf2f(((const __hip_bfloat16*)p)[i]);
  else      return ((const float*)p)[i];
}
template <bool BF16>
__device__ __forceinline__ void stout(void* p, size_t i, float v) {
  if (BF16) ((__hip_bfloat16*)p)[i] = __float2bfloat16(v);
  else      ((float*)p)[i] = v;
}

// Detect input dtype: bf16 ray-direction norms are ~1; f32 misread as bf16 is garbage.
__global__ void detect_kernel(const void* __restrict__ rdv, float* __restrict__ ws) {
  int lane = threadIdx.x;  // 64 threads
  const __hip_bfloat16* p = (const __hip_bfloat16*)rdv;
  float x = bf2f(p[lane * 3 + 0]);
  float y = bf2f(p[lane * 3 + 1]);
  float z = bf2f(p[lane * 3 + 2]);
  float n2 = x * x + y * y + z * z;
  bool ok = (n2 > 0.95f) && (n2 < 1.05f);
  unsigned long long m = __ballot(ok);
  if (lane == 0) *((int*)(ws + WS_FLAG)) = (m == ~0ull) ? 1 : 0;
}

template <bool BF16>
__global__ void prep_kernel(const void* __restrict__ W1,
                            const void* __restrict__ b1,
                            const void* __restrict__ W2,
                            const void* __restrict__ b2,
                            float* __restrict__ ws) {
  if ((*((const int*)(ws + WS_FLAG)) != 0) != BF16) return;
  int tid = blockIdx.x * blockDim.x + threadIdx.x;
  if (tid < 15360) ws[WS_W1 + tid] = ldin<BF16>(W1, tid);
  if (tid < 256)   ws[WS_W2 + tid] = ldin<BF16>(W2, tid);
  if (tid < 64)    ws[WS_B1 + tid] = ldin<BF16>(b1, tid);
  if (tid < 4)     ws[WS_B2 + tid] = ldin<BF16>(b2, tid);
}

// planes[p][c][y][x]  ->  planesT[p][y][x][c] (f32). Write-coalesced.
template <bool BF16>
__global__ void transpose_kernel(const void* __restrict__ planes, float* __restrict__ ws) {
  if ((*((const int*)(ws + WS_FLAG)) != 0) != BF16) return;
  int tid = blockIdx.x * blockDim.x + threadIdx.x;
  if (tid >= 3 * 64 * 64 * 80) return;
  int c  = tid % 80;
  int x  = (tid / 80) % 64;
  int y  = (tid / (80 * 64)) % 64;
  int p  = tid / (80 * 64 * 64);
  ws[WS_PT + tid] = ldin<BF16>(planes, ((size_t)(p * 80 + c) * 64 + y) * 64 + x);
}

// ---------- shared per-plane sample math ----------
struct TapInfo {
  float w00, w10, w01, w11;
  int o00, o10, o01, o11;   // texel indices (y*64+x)
};
__device__ __forceinline__ TapInfo tap_setup(float u, float v) {
  TapInfo t;
  float fx = u * 32.0f + 31.5f;
  float fy = v * 32.0f + 31.5f;
  float flx = floorf(fx), fly = floorf(fy);
  int x0 = (int)flx, y0 = (int)fly;
  float wx = fx - flx, wy = fy - fly;
  int x1 = x0 + 1, y1 = y0 + 1;
  bool vx0 = (x0 >= 0) && (x0 < 64);
  bool vx1 = (x1 >= 0) && (x1 < 64);
  bool vy0 = (y0 >= 0) && (y0 < 64);
  bool vy1 = (y1 >= 0) && (y1 < 64);
  int cx0 = min(max(x0, 0), 63), cx1 = min(max(x1, 0), 63);
  int cy0 = min(max(y0, 0), 63), cy1 = min(max(y1, 0), 63);
  t.w00 = (1.0f - wx) * (1.0f - wy) * ((vx0 && vy0) ? 1.0f : 0.0f);
  t.w10 = wx * (1.0f - wy)          * ((vx1 && vy0) ? 1.0f : 0.0f);
  t.w01 = (1.0f - wx) * wy          * ((vx0 && vy1) ? 1.0f : 0.0f);
  t.w11 = wx * wy                   * ((vx1 && vy1) ? 1.0f : 0.0f);
  t.o00 = cy0 * 64 + cx0; t.o10 = cy0 * 64 + cx1;
  t.o01 = cy1 * 64 + cx0; t.o11 = cy1 * 64 + cx1;
  return t;
}

// ---------- transposed-layout decode: float4 taps, software-pipelined ----------
template <int NOUT>
__device__ __forceinline__ void mlp_decode_t(const float* __restrict__ planesT,
                                             const float* __restrict__ W1f,
                                             const float* __restrict__ b1f,
                                             const float* __restrict__ W2f,
                                             const float* __restrict__ b2v,
                                             float px, float py, float pz,
                                             float* o) {
  float h[HID];
  #pragma unroll
  for (int j = 0; j < HID; j++) h[j] = b1f[j];

  const float inv = 1.0f / 0.6f;
  float u3[3] = { px * inv, py * inv, pz * inv };

  #pragma unroll 1
  for (int p = 0; p < 3; p++) {
    float u = (p == 2) ? u3[1] : u3[0];
    float v = (p == 0) ? u3[1] : u3[2];
    TapInfo t = tap_setup(u, v);
    const float* base = planesT + p * (64 * 64 * 80);
    const float4* p00 = (const float4*)(base + t.o00 * 80);
    const float4* p10 = (const float4*)(base + t.o10 * 80);
    const float4* p01 = (const float4*)(base + t.o01 * 80);
    const float4* p11 = (const float4*)(base + t.o11 * 80);
    float4 c00 = p00[0], c10 = p10[0], c01 = p01[0], c11 = p11[0];
    const float* wr = W1f + p * (CCH * HID);
    #pragma unroll 1
    for (int g = 0; g < 20; g++) {
      int gn = min(g + 1, 19);
      float4 n00 = p00[gn], n10 = p10[gn], n01 = p01[gn], n11 = p11[gn];
      float f0 = t.w00 * c00.x + t.w10 * c10.x + t.w01 * c01.x + t.w11 * c11.x;
      float f1 = t.w00 * c00.y + t.w10 * c10.y + t.w01 * c01.y + t.w11 * c11.y;
      float f2 = t.w00 * c00.z + t.w10 * c10.z + t.w01 * c01.z + t.w11 * c11.z;
      float f3 = t.w00 * c00.w + t.w10 * c10.w + t.w01 * c01.w + t.w11 * c11.w;
      const float* w0 = wr + (g * 4) * HID;   // wave-uniform -> s_load
      #pragma unroll
      for (int j = 0; j < HID; j++) {
        float hj = h[j];
        hj = fmaf(f0, w0[j], hj);
        hj = fmaf(f1, w0[HID + j], hj);
        hj = fmaf(f2, w0[2 * HID + j], hj);
        hj = fmaf(f3, w0[3 * HID + j], hj);
        h[j] = hj;
      }
      c00 = n00; c10 = n10; c01 = n01; c11 = n11;
    }
  }

  #pragma unroll
  for (int i = 0; i < NOUT; i++) o[i] = b2v[i];
  #pragma unroll
  for (int j = 0; j < HID; j++) {
    float hr = fmaxf(h[j], 0.0f);
    #pragma unroll
    for (int i = 0; i < NOUT; i++) o[i] = fmaf(hr, W2f[j * 4 + i], o[i]);
  }
}

// ---------- fallback gather decode (original) ----------
template <bool BF16, int NOUT>
__device__ __forceinline__ void mlp_decode_g(const void* __restrict__ planes,
                                             const float* __restrict__ W1f,
                                             const float* __restrict__ b1f,
                                             const float* __restrict__ W2f,
                                             const float* __restrict__ b2v,
                                             float px, float py, float pz,
                                             float* o) {
  float h[HID];
  #pragma unroll
  for (int j = 0; j < HID; j++) h[j] = b1f[j];
  const float inv = 1.0f / 0.6f;
  float u3[3] = { px * inv, py * inv, pz * inv };
  #pragma unroll 1
  for (int p = 0; p < 3; p++) {
    float u = (p == 2) ? u3[1] : u3[0];
    float v = (p == 0) ? u3[1] : u3[2];
    TapInfo t = tap_setup(u, v);
    size_t pbase = (size_t)p * CCH * 4096;
    const float* wbase = W1f + p * CCH * HID;
    #pragma unroll 1
    for (int c = 0; c < CCH; c++) {
      size_t cb = pbase + (size_t)c * 4096;
      float f = t.w00 * ldin<BF16>(planes, cb + t.o00) + t.w10 * ldin<BF16>(planes, cb + t.o10)
              + t.w01 * ldin<BF16>(planes, cb + t.o01) + t.w11 * ldin<BF16>(planes, cb + t.o11);
      const float* wr = wbase + c * HID;
      #pragma unroll
      for (int j = 0; j < HID; j++) h[j] = fmaf(f, wr[j], h[j]);
    }
  }
  #pragma unroll
  for (int i = 0; i < NOUT; i++) o[i] = b2v[i];
  #pragma unroll
  for (int j = 0; j < HID; j++) {
    float hr = fmaxf(h[j], 0.0f);
    #pragma unroll
    for (int i = 0; i < NOUT; i++) o[i] = fmaf(hr, W2f[j * 4 + i], o[i]);
  }
}

#define RAYS_PER_BLOCK 2
#define BLOCK_T (RAYS_PER_BLOCK * S_PER)   // 192

// USE_T: 1 = transposed-plane fast path, 0 = gather fallback
template <bool BF16, int USE_T>
__global__ __launch_bounds__(BLOCK_T) void fused_kernel(
    const void* __restrict__ planes,
    const void* __restrict__ ro,
    const void* __restrict__ rd,
    const float* __restrict__ ws,
    void* __restrict__ out) {
  if ((*((const int*)(ws + WS_FLAG)) != 0) != BF16) return;

  __shared__ float rec[RAYS_PER_BLOCK][S_PER][8];

  int tid = threadIdx.x;
  int sidx = tid % S_PER;
  int rloc = tid / S_PER;
  int ray = blockIdx.x * RAYS_PER_BLOCK + rloc;
  int gid = ray * S_PER + sidx;

  float ox = ldin<BF16>(ro, ray*3+0), oy = ldin<BF16>(ro, ray*3+1), oz = ldin<BF16>(ro, ray*3+2);
  float dx = ldin<BF16>(rd, ray*3+0), dy = ldin<BF16>(rd, ray*3+1), dz = ldin<BF16>(rd, ray*3+2);
  float o3[3] = {ox, oy, oz}, d3[3] = {dx, dy, dz};
  float tmin = -1e30f, tmax = 1e30f;
  #pragma unroll
  for (int k = 0; k < 3; k++) {
    float sd = (fabsf(d3[k]) < 1e-9f) ? 1e-9f : d3[k];
    float ta = (-0.6f - o3[k]) / sd;
    float tb = ( 0.6f - o3[k]) / sd;
    tmin = fmaxf(tmin, fminf(ta, tb));
    tmax = fminf(tmax, fmaxf(ta, tb));
  }
  float tn = fmaxf(tmin, 0.0f);
  float span = fmaxf(tmax - tn, 0.0f);

  float frac = ((float)sidx + 0.5f) * (1.0f / (float)S_PER);
  float depth = tn + span * frac;
  float px = ox + depth * dx;
  float py = oy + depth * dy;
  float pz = oz + depth * dz;

  const float* W1f = ws + WS_W1;
  const float* W2f = ws + WS_W2;
  const float* b1f = ws + WS_B1;
  const float* b2v = ws + WS_B2;
  const float* planesT = ws + WS_PT;

  float o4[4];
  if (USE_T) mlp_decode_t<4>(planesT, W1f, b1f, W2f, b2v, px, py, pz, o4);
  else       mlp_decode_g<BF16, 4>(planes, W1f, b1f, W2f, b2v, px, py, pz, o4);
  float sdf0 = o4[0];

  float g[3];
  #pragma unroll 1
  for (int i = 0; i < 3; i++) {
    float qx = px + ((i == 0) ? 0.01f : 0.0f);
    float qy = py + ((i == 1) ? 0.01f : 0.0f);
    float qz = pz + ((i == 2) ? 0.01f : 0.0f);
    qx = fminf(fmaxf(qx, -0.6f), 0.6f);
    qy = fminf(fmaxf(qy, -0.6f), 0.6f);
    qz = fminf(fmaxf(qz, -0.6f), 0.6f);
    float so[1];
    if (USE_T) mlp_decode_t<1>(planesT, W1f, b1f, W2f, b2v, qx, qy, qz, so);
    else       mlp_decode_g<BF16, 1>(planes, W1f, b1f, W2f, b2v, qx, qy, qz, so);
    g[i] = (so[0] - sdf0) * 100.0f;   // / EPS_FD
  }

  stout<BF16>(out, (size_t)32768 + (size_t)gid*3+0, g[0]);
  stout<BF16>(out, (size_t)32768 + (size_t)gid*3+1, g[1]);
  stout<BF16>(out, (size_t)32768 + (size_t)gid*3+2, g[2]);

  float cr = 1.0f / (1.0f + expf(-o4[1])) * 1.002f - 0.001f;
  float cg = 1.0f / (1.0f + expf(-o4[2])) * 1.002f - 0.001f;
  float cb = 1.0f / (1.0f + expf(-o4[3])) * 1.002f - 0.001f;
  float pn = sqrtf(px*px + py*py + pz*pz);

  rec[rloc][sidx][0] = sdf0;
  rec[rloc][sidx][1] = cr;
  rec[rloc][sidx][2] = cg;
  rec[rloc][sidx][3] = cb;
  rec[rloc][sidx][4] = g[0];
  rec[rloc][sidx][5] = g[1];
  rec[rloc][sidx][6] = g[2];
  rec[rloc][sidx][7] = pn;

  __syncthreads();

  if (sidx == 0) {
    float delta = span * (1.0f / (float)S_PER);
    float T = 1.0f, wsum = 0.0f, dep = 0.0f;
    float rgb[3] = {0.f, 0.f, 0.f};
    float nrm[3] = {0.f, 0.f, 0.f};

    #pragma unroll 1
    for (int s = 0; s < S_PER; s++) {
      float a0 = rec[rloc][s][0];
      float a1 = rec[rloc][s][1];
      float a2 = rec[rloc][s][2];
      float a3 = rec[rloc][s][3];
      float bx = rec[rloc][s][4];
      float by = rec[rloc][s][5];
      float bz = rec[rloc][s][6];
      float bw = rec[rloc][s][7];
      float dpt = tn + span * (((float)s + 0.5f) * (1.0f / (float)S_PER));
      float shifted = a0 + bw - 0.5f;
      float xarg = -shifted * 80.0f;
      float sigma = (xarg > 20.0f) ? xarg : log1pf(expf(xarg));
      float alpha = 1.0f - expf(-sigma * delta);
      float w = alpha * T;
      T = T * (1.0f - alpha + 1e-10f);
      wsum += w;
      dep += w * dpt;
      rgb[0] += w * a1; rgb[1] += w * a2; rgb[2] += w * a3;
      float gl = sqrtf(bx*bx + by*by + bz*bz) + 1e-8f;
      float igl = 1.0f / gl;
      nrm[0] += w * bx * igl; nrm[1] += w * by * igl; nrm[2] += w * bz * igl;
    }

    rgb[0] += 1.0f - wsum; rgb[1] += 1.0f - wsum; rgb[2] += 1.0f - wsum;
    float nl = sqrtf(nrm[0]*nrm[0] + nrm[1]*nrm[1] + nrm[2]*nrm[2]) + 1e-8f;
    float inl = 1.0f / nl;

    #pragma unroll
    for (int c = 0; c < 3; c++) {
      float n = (nrm[c] * inl + 1.0f) * 0.5f * wsum;
      stout<BF16>(out, (size_t)(c*4096 + ray), rgb[c]);
      stout<BF16>(out, (size_t)(20480 + c*4096 + ray), n);
    }
    stout<BF16>(out, (size_t)(12288 + ray), dep);
    stout<BF16>(out, (size_t)(16384 + ray), wsum);
  }
}

extern "C" void kernel_launch(void* const* d_in, const int* in_sizes, int n_in,
                              void* d_out, int out_size, void* d_ws, size_t ws_size,
                              hipStream_t stream) {
  const void* planes = d_in[0];
  const void* ro     = d_in[1];
  const void* rd     = d_in[2];
  const void* W1     = d_in[3];
  const void* b1     = d_in[4];
  const void* W2     = d_in[5];
  const void* b2     = d_in[6];
  float* ws = (float*)d_ws;

  detect_kernel<<<1, 64, 0, stream>>>(rd, ws);
  prep_kernel<false><<<60, 256, 0, stream>>>(W1, b1, W2, b2, ws);
  prep_kernel<true ><<<60, 256, 0, stream>>>(W1, b1, W2, b2, ws);

  if (ws_size >= WS_NEEDED_BYTES) {
    transpose_kernel<false><<<3840, 256, 0, stream>>>(planes, ws);
    transpose_kernel<true ><<<3840, 256, 0, stream>>>(planes, ws);
    fused_kernel<false, 1><<<NUM_RAYS / RAYS_PER_BLOCK, BLOCK_T, 0, stream>>>(planes, ro, rd, ws, d_out);
    fused_kernel<true,  1><<<NUM_RAYS / RAYS_PER_BLOCK, BLOCK_T, 0, stream>>>(planes, ro, rd, ws, d_out);
  } else {
    fused_kernel<false, 0><<<NUM_RAYS / RAYS_PER_BLOCK, BLOCK_T, 0, stream>>>(planes, ro, rd, ws, d_out);
    fused_kernel<true,  0><<<NUM_RAYS / RAYS_PER_BLOCK, BLOCK_T, 0, stream>>>(planes, ro, rd, ws, d_out);
  }
}

// Round 5
// 1045.805 us; speedup vs baseline: 2.2116x; 1.1353x over previous
//
#include <hip/hip_runtime.h>
#include <hip/hip_bf16.h>

#define NUM_RAYS 4096
#define S_PER 96
#define NPTS (NUM_RAYS * S_PER)
#define CCH 80
#define HID 64
#define KPAD 256

// ws layout (byte offsets)
#define WSB_FLAG   0         // int
#define WSB_W2     256       // 256 f32 (64x4)
#define WSB_B1     1536      // 64 f32
#define WSB_B2     1856      // 4 f32
#define WSB_W1T    4096      // 16384 bf16: W1T[n][k] n<64, k<256 (k>=240 zero)
#define WSB_PT     40960     // 983040 bf16: planesT [p][y*64+x][80]
#define WS_NEEDED  (WSB_PT + (size_t)3*4096*80*2)

// d_out layout (elements of output dtype):
// [0) comp_rgb 3*4096 | [12288) depth 4096 | [16384) opacity 4096
// [20480) comp_normal 3*4096 | [32768) sdf_grad 393216*3

typedef __attribute__((ext_vector_type(8))) short short8;
typedef __attribute__((ext_vector_type(4))) float f32x4;

__device__ __forceinline__ float bf2f(__hip_bfloat16 v) { return __bfloat162float(v); }

__device__ __forceinline__ short f2bs(float f) {
  __hip_bfloat16 h = __float2bfloat16(f);
  short s; __builtin_memcpy(&s, &h, 2); return s;
}

template <bool BF16>
__device__ __forceinline__ float ldin(const void* p, size_t i) {
  if (BF16) return bf2f(((const __hip_bfloat16*)p)[i]);
  else      return ((const float*)p)[i];
}
template <bool BF16>
__device__ __forceinline__ void stout(void* p, size_t i, float v) {
  if (BF16) ((__hip_bfloat16*)p)[i] = __float2bfloat16(v);
  else      ((float*)p)[i] = v;
}

__device__ __forceinline__ float bflo(unsigned u) { return __uint_as_float(u << 16); }
__device__ __forceinline__ float bfhi(unsigned u) { return __uint_as_float(u & 0xffff0000u); }

// Detect input dtype: bf16 ray-direction norms are ~1; f32 misread as bf16 is garbage.
__global__ void detect_kernel(const void* __restrict__ rdv, float* __restrict__ ws) {
  int lane = threadIdx.x;  // 64 threads
  const __hip_bfloat16* p = (const __hip_bfloat16*)rdv;
  float x = bf2f(p[lane * 3 + 0]);
  float y = bf2f(p[lane * 3 + 1]);
  float z = bf2f(p[lane * 3 + 2]);
  float n2 = x * x + y * y + z * z;
  bool ok = (n2 > 0.95f) && (n2 < 1.05f);
  unsigned long long m = __ballot(ok);
  if (lane == 0) *((int*)((char*)ws + WSB_FLAG)) = (m == ~0ull) ? 1 : 0;
}

template <bool BF16>
__global__ void prep_kernel(const void* __restrict__ W1,
                            const void* __restrict__ b1,
                            const void* __restrict__ W2,
                            const void* __restrict__ b2,
                            float* __restrict__ ws) {
  if ((*((const int*)((char*)ws + WSB_FLAG)) != 0) != BF16) return;
  int tid = blockIdx.x * blockDim.x + threadIdx.x;  // 64*256 = 16384
  unsigned short* w1t = (unsigned short*)((char*)ws + WSB_W1T);
  if (tid < 64 * KPAD) {
    int n = tid >> 8, k = tid & 255;
    float v = (k < 240) ? ldin<BF16>(W1, (size_t)k * 64 + n) : 0.0f;
    w1t[tid] = (unsigned short)f2bs(v);
  }
  float* w2f = (float*)((char*)ws + WSB_W2);
  float* b1f = (float*)((char*)ws + WSB_B1);
  float* b2f = (float*)((char*)ws + WSB_B2);
  if (tid < 256) w2f[tid] = ldin<BF16>(W2, tid);
  if (tid < 64)  b1f[tid] = ldin<BF16>(b1, tid);
  if (tid < 4)   b2f[tid] = ldin<BF16>(b2, tid);
}

// planes[p][c][y][x] -> planesT[p][y*64+x][80] (bf16, channel-last)
template <bool BF16>
__global__ void transpose_kernel(const void* __restrict__ planes, float* __restrict__ ws) {
  if ((*((const int*)((char*)ws + WSB_FLAG)) != 0) != BF16) return;
  int tid = blockIdx.x * blockDim.x + threadIdx.x;
  if (tid >= 3 * 4096 * 80) return;
  int c   = tid % 80;
  int tex = (tid / 80) & 4095;
  int p   = tid / (80 * 4096);
  unsigned short* ptb = (unsigned short*)((char*)ws + WSB_PT);
  float v = ldin<BF16>(planes, ((size_t)(p * 80 + c) * 4096) + tex);
  ptb[tid] = (unsigned short)f2bs(v);
}

struct TapInfo {
  float w00, w10, w01, w11;
  int o00, o10, o01, o11;   // texel indices (y*64+x)
};
__device__ __forceinline__ TapInfo tap_setup(float u, float v) {
  TapInfo t;
  float fx = u * 32.0f + 31.5f;
  float fy = v * 32.0f + 31.5f;
  float flx = floorf(fx), fly = floorf(fy);
  int x0 = (int)flx, y0 = (int)fly;
  float wx = fx - flx, wy = fy - fly;
  int x1 = x0 + 1, y1 = y0 + 1;
  bool vx0 = (x0 >= 0) && (x0 < 64);
  bool vx1 = (x1 >= 0) && (x1 < 64);
  bool vy0 = (y0 >= 0) && (y0 < 64);
  bool vy1 = (y1 >= 0) && (y1 < 64);
  int cx0 = min(max(x0, 0), 63), cx1 = min(max(x1, 0), 63);
  int cy0 = min(max(y0, 0), 63), cy1 = min(max(y1, 0), 63);
  t.w00 = (1.0f - wx) * (1.0f - wy) * ((vx0 && vy0) ? 1.0f : 0.0f);
  t.w10 = wx * (1.0f - wy)          * ((vx1 && vy0) ? 1.0f : 0.0f);
  t.w01 = (1.0f - wx) * wy          * ((vx0 && vy1) ? 1.0f : 0.0f);
  t.w11 = wx * wy                   * ((vx1 && vy1) ? 1.0f : 0.0f);
  t.o00 = cy0 * 64 + cx0; t.o10 = cy0 * 64 + cx1;
  t.o01 = cy1 * 64 + cx0; t.o11 = cy1 * 64 + cx1;
  return t;
}

#define SEL3(pl, a, b, c) ((pl) == 0 ? (a) : ((pl) == 1 ? (b) : (c)))

// Block = 1 ray: 4 waves x 6 iterations x (4 samples x 4 decodes = 16 MFMA rows).
template <bool BF16>
__global__ __launch_bounds__(256) void fused_kernel(
    const void* __restrict__ ro,
    const void* __restrict__ rd,
    const float* __restrict__ ws,
    void* __restrict__ out) {
  if ((*((const int*)((const char*)ws + WSB_FLAG)) != 0) != BF16) return;

  __shared__ unsigned short w1s[64 * 264];   // W1T padded rows (264 shorts)
  __shared__ float rec[S_PER][8];

  const unsigned short* w1t = (const unsigned short*)((const char*)ws + WSB_W1T);
  const unsigned short* ptb = (const unsigned short*)((const char*)ws + WSB_PT);
  const float* w2f = (const float*)((const char*)ws + WSB_W2);
  const float* b1f = (const float*)((const char*)ws + WSB_B1);
  const float* b2f = (const float*)((const char*)ws + WSB_B2);

  int tid = threadIdx.x;
  int wave = tid >> 6;
  int lane = tid & 63;
  int lane15 = lane & 15;
  int quad = lane >> 4;
  int ray = blockIdx.x;

  // stage W1T into LDS: 2048 16B chunks, 8 per thread
  #pragma unroll
  for (int t = 0; t < 8; t++) {
    int id = tid + t * 256;           // chunk id
    int n = id >> 5;                  // 32 chunks per row
    int k8 = (id & 31) * 8;
    uint4 v = *(const uint4*)(w1t + n * 256 + k8);
    *(uint4*)(w1s + n * 264 + k8) = v;
  }

  // ray data (uniform across block)
  float ox = ldin<BF16>(ro, (size_t)ray*3+0), oy = ldin<BF16>(ro, (size_t)ray*3+1), oz = ldin<BF16>(ro, (size_t)ray*3+2);
  float dx = ldin<BF16>(rd, (size_t)ray*3+0), dy = ldin<BF16>(rd, (size_t)ray*3+1), dz = ldin<BF16>(rd, (size_t)ray*3+2);
  float o3[3] = {ox, oy, oz}, d3[3] = {dx, dy, dz};
  float tmin = -1e30f, tmax = 1e30f;
  #pragma unroll
  for (int k = 0; k < 3; k++) {
    float sd = (fabsf(d3[k]) < 1e-9f) ? 1e-9f : d3[k];
    float ta = (-0.6f - o3[k]) / sd;
    float tb = ( 0.6f - o3[k]) / sd;
    tmin = fmaxf(tmin, fminf(ta, tb));
    tmax = fminf(tmax, fmaxf(ta, tb));
  }
  float tn = fmaxf(tmin, 0.0f);
  float span = fmaxf(tmax - tn, 0.0f);

  // persistent per-lane weights
  float W2v[4][4], b1v[4];
  #pragma unroll
  for (int nb = 0; nb < 4; nb++) {
    b1v[nb] = b1f[nb * 16 + lane15];
    #pragma unroll
    for (int i = 0; i < 4; i++) W2v[nb][i] = w2f[(nb * 16 + lane15) * 4 + i];
  }
  float b2v[4];
  #pragma unroll
  for (int i = 0; i < 4; i++) b2v[i] = b2f[i];

  __syncthreads();

  #pragma unroll 1
  for (int it = 0; it < 6; it++) {
    int sbase = it * 16 + wave * 4;

    // ---- feature stage: this lane feeds A-row m = lane15 (sample sF, decode d)
    int sF = sbase + (lane15 >> 2);
    int d  = lane15 & 3;
    float depF = tn + span * (((float)sF + 0.5f) * (1.0f / (float)S_PER));
    float px = ox + depF * dx, py = oy + depF * dy, pz = oz + depF * dz;
    if (d == 1) px += 0.01f;
    if (d == 2) py += 0.01f;
    if (d == 3) pz += 0.01f;
    if (d > 0) {
      px = fminf(fmaxf(px, -0.6f), 0.6f);
      py = fminf(fmaxf(py, -0.6f), 0.6f);
      pz = fminf(fmaxf(pz, -0.6f), 0.6f);
    }
    const float inv = 1.0f / 0.6f;
    float ux = px * inv, uy = py * inv, uz = pz * inv;
    TapInfo t0 = tap_setup(ux, uy);   // plane 0: (x,y)
    TapInfo t1 = tap_setup(ux, uz);   // plane 1: (x,z)
    TapInfo t2 = tap_setup(uy, uz);   // plane 2: (y,z)
    // per-plane global short-index bases: (pl*4096 + texel)*80
    int p0b00 = t0.o00 * 80,              p0b10 = t0.o10 * 80,              p0b01 = t0.o01 * 80,              p0b11 = t0.o11 * 80;
    int p1b00 = (4096 + t1.o00) * 80,     p1b10 = (4096 + t1.o10) * 80,     p1b01 = (4096 + t1.o01) * 80,     p1b11 = (4096 + t1.o11) * 80;
    int p2b00 = (8192 + t2.o00) * 80,     p2b10 = (8192 + t2.o10) * 80,     p2b01 = (8192 + t2.o01) * 80,     p2b11 = (8192 + t2.o11) * 80;

    f32x4 acc[4];
    #pragma unroll
    for (int nb = 0; nb < 4; nb++) acc[nb] = (f32x4){0.f, 0.f, 0.f, 0.f};

    #pragma unroll
    for (int cc = 0; cc < 8; cc++) {
      int kb = 32 * cc + 8 * quad;
      short8 afr;
      if (kb < 240) {
        int pl = (kb >= 160) ? 2 : ((kb >= 80) ? 1 : 0);
        int ch = kb - pl * 80;
        int a00 = SEL3(pl, p0b00, p1b00, p2b00) + ch;
        int a10 = SEL3(pl, p0b10, p1b10, p2b10) + ch;
        int a01 = SEL3(pl, p0b01, p1b01, p2b01) + ch;
        int a11 = SEL3(pl, p0b11, p1b11, p2b11) + ch;
        float w00 = SEL3(pl, t0.w00, t1.w00, t2.w00);
        float w10 = SEL3(pl, t0.w10, t1.w10, t2.w10);
        float w01 = SEL3(pl, t0.w01, t1.w01, t2.w01);
        float w11 = SEL3(pl, t0.w11, t1.w11, t2.w11);
        uint4 q00 = *(const uint4*)(ptb + a00);
        uint4 q10 = *(const uint4*)(ptb + a10);
        uint4 q01 = *(const uint4*)(ptb + a01);
        uint4 q11 = *(const uint4*)(ptb + a11);
        unsigned u00[4] = {q00.x, q00.y, q00.z, q00.w};
        unsigned u10[4] = {q10.x, q10.y, q10.z, q10.w};
        unsigned u01[4] = {q01.x, q01.y, q01.z, q01.w};
        unsigned u11[4] = {q11.x, q11.y, q11.z, q11.w};
        #pragma unroll
        for (int q = 0; q < 4; q++) {
          float flo = w00 * bflo(u00[q]) + w10 * bflo(u10[q]) + w01 * bflo(u01[q]) + w11 * bflo(u11[q]);
          float fhi = w00 * bfhi(u00[q]) + w10 * bfhi(u10[q]) + w01 * bfhi(u01[q]) + w11 * bfhi(u11[q]);
          afr[2 * q]     = f2bs(flo);
          afr[2 * q + 1] = f2bs(fhi);
        }
      } else {
        #pragma unroll
        for (int j = 0; j < 8; j++) afr[j] = 0;
      }
      #pragma unroll
      for (int nb = 0; nb < 4; nb++) {
        short8 bfr = *(const short8*)(w1s + (nb * 16 + lane15) * 264 + 8 * quad + 32 * cc);
        acc[nb] = __builtin_amdgcn_mfma_f32_16x16x32_bf16(afr, bfr, acc[nb], 0, 0, 0);
      }
    }

    // ---- layer 2: lane holds h[m=quad*4+reg][n=nb*16+lane15] = acc[nb][reg] + b1[n]
    float part[4][4];
    #pragma unroll
    for (int reg = 0; reg < 4; reg++) {
      #pragma unroll
      for (int i = 0; i < 4; i++) part[reg][i] = 0.0f;
      #pragma unroll
      for (int nb = 0; nb < 4; nb++) {
        float hr = fmaxf(acc[nb][reg] + b1v[nb], 0.0f);
        #pragma unroll
        for (int i = 0; i < 4; i++) part[reg][i] = fmaf(hr, W2v[nb][i], part[reg][i]);
      }
    }
    // butterfly over the 4 lane15 bits -> full sums replicated in 16-lane group
    #pragma unroll
    for (int mask = 1; mask < 16; mask <<= 1) {
      #pragma unroll
      for (int reg = 0; reg < 4; reg++)
        #pragma unroll
        for (int i = 0; i < 4; i++)
          part[reg][i] += __shfl_xor(part[reg][i], mask, 64);
    }

    // ---- epilogue: this lane's quad owns sample sE (rows quad*4..quad*4+3)
    int sE = sbase + quad;
    float outv[4][4];
    #pragma unroll
    for (int reg = 0; reg < 4; reg++)
      #pragma unroll
      for (int i = 0; i < 4; i++) outv[reg][i] = part[reg][i] + b2v[i];

    float sdf0 = outv[0][0];
    float g0 = (outv[1][0] - sdf0) * 100.0f;
    float g1 = (outv[2][0] - sdf0) * 100.0f;
    float g2 = (outv[3][0] - sdf0) * 100.0f;
    float cr = 1.0f / (1.0f + expf(-outv[0][1])) * 1.002f - 0.001f;
    float cg = 1.0f / (1.0f + expf(-outv[0][2])) * 1.002f - 0.001f;
    float cb = 1.0f / (1.0f + expf(-outv[0][3])) * 1.002f - 0.001f;
    float depE = tn + span * (((float)sE + 0.5f) * (1.0f / (float)S_PER));
    float ex = ox + depE * dx, ey = oy + depE * dy, ez = oz + depE * dz;
    float pn = sqrtf(ex * ex + ey * ey + ez * ez);

    if (lane15 == 0) {
      rec[sE][0] = sdf0; rec[sE][1] = cr; rec[sE][2] = cg; rec[sE][3] = cb;
      rec[sE][4] = g0;   rec[sE][5] = g1; rec[sE][6] = g2; rec[sE][7] = pn;
      size_t gid = (size_t)ray * S_PER + sE;
      stout<BF16>(out, (size_t)32768 + gid * 3 + 0, g0);
      stout<BF16>(out, (size_t)32768 + gid * 3 + 1, g1);
      stout<BF16>(out, (size_t)32768 + gid * 3 + 2, g2);
    }
  }

  __syncthreads();

  if (tid == 0) {
    float delta = span * (1.0f / (float)S_PER);
    float T = 1.0f, wsum = 0.0f, dep = 0.0f;
    float rgb[3] = {0.f, 0.f, 0.f};
    float nrm[3] = {0.f, 0.f, 0.f};

    #pragma unroll 1
    for (int s = 0; s < S_PER; s++) {
      float a0 = rec[s][0], a1 = rec[s][1], a2 = rec[s][2], a3 = rec[s][3];
      float bx = rec[s][4], by = rec[s][5], bz = rec[s][6], bw = rec[s][7];
      float dpt = tn + span * (((float)s + 0.5f) * (1.0f / (float)S_PER));
      float shifted = a0 + bw - 0.5f;
      float xarg = -shifted * 80.0f;
      float sigma = (xarg > 20.0f) ? xarg : log1pf(expf(xarg));
      float alpha = 1.0f - expf(-sigma * delta);
      float w = alpha * T;
      T = T * (1.0f - alpha + 1e-10f);
      wsum += w;
      dep += w * dpt;
      rgb[0] += w * a1; rgb[1] += w * a2; rgb[2] += w * a3;
      float gl = sqrtf(bx * bx + by * by + bz * bz) + 1e-8f;
      float igl = 1.0f / gl;
      nrm[0] += w * bx * igl; nrm[1] += w * by * igl; nrm[2] += w * bz * igl;
    }

    rgb[0] += 1.0f - wsum; rgb[1] += 1.0f - wsum; rgb[2] += 1.0f - wsum;
    float nl = sqrtf(nrm[0] * nrm[0] + nrm[1] * nrm[1] + nrm[2] * nrm[2]) + 1e-8f;
    float inl = 1.0f / nl;

    #pragma unroll
    for (int c = 0; c < 3; c++) {
      float n = (nrm[c] * inl + 1.0f) * 0.5f * wsum;
      stout<BF16>(out, (size_t)(c * 4096 + ray), rgb[c]);
      stout<BF16>(out, (size_t)(20480 + c * 4096 + ray), n);
    }
    stout<BF16>(out, (size_t)(12288 + ray), dep);
    stout<BF16>(out, (size_t)(16384 + ray), wsum);
  }
}

extern "C" void kernel_launch(void* const* d_in, const int* in_sizes, int n_in,
                              void* d_out, int out_size, void* d_ws, size_t ws_size,
                              hipStream_t stream) {
  const void* planes = d_in[0];
  const void* ro     = d_in[1];
  const void* rd     = d_in[2];
  const void* W1     = d_in[3];
  const void* b1     = d_in[4];
  const void* W2     = d_in[5];
  const void* b2     = d_in[6];
  float* ws = (float*)d_ws;

  detect_kernel<<<1, 64, 0, stream>>>(rd, ws);
  prep_kernel<false><<<64, 256, 0, stream>>>(W1, b1, W2, b2, ws);
  prep_kernel<true ><<<64, 256, 0, stream>>>(W1, b1, W2, b2, ws);
  transpose_kernel<false><<<3840, 256, 0, stream>>>(planes, ws);
  transpose_kernel<true ><<<3840, 256, 0, stream>>>(planes, ws);
  fused_kernel<false><<<NUM_RAYS, 256, 0, stream>>>(ro, rd, ws, d_out);
  fused_kernel<true ><<<NUM_RAYS, 256, 0, stream>>>(ro, rd, ws, d_out);
}

// Round 6
// 612.771 us; speedup vs baseline: 3.7745x; 1.7067x over previous
//
#include <hip/hip_runtime.h>
#include <hip/hip_bf16.h>

#define NUM_RAYS 4096
#define S_PER 96
#define NPTS (NUM_RAYS * S_PER)
#define CCH 80
#define HID 64

// ws layout (byte offsets)
#define WSB_FLAG   0         // int
#define WSB_W2     256       // 256 f32 (64x4)
#define WSB_B1     1536      // 64 f32
#define WSB_B2     1856      // 4 f32
#define WSB_W1S    4096      // 16384 bf16 shorts, swizzled [cc][nb][lane][8]
#define WSB_PT     40960     // 983040 bf16: planesT [p][y*64+x][80]

// d_out layout (elements of output dtype):
// [0) comp_rgb 3*4096 | [12288) depth 4096 | [16384) opacity 4096
// [20480) comp_normal 3*4096 | [32768) sdf_grad 393216*3

typedef __attribute__((ext_vector_type(8))) short short8;
typedef __attribute__((ext_vector_type(4))) float f32x4;

__device__ __forceinline__ float bf2f(__hip_bfloat16 v) { return __bfloat162float(v); }

__device__ __forceinline__ short f2bs(float f) {
  __hip_bfloat16 h = __float2bfloat16(f);
  short s; __builtin_memcpy(&s, &h, 2); return s;
}

template <bool BF16>
__device__ __forceinline__ float ldin(const void* p, size_t i) {
  if (BF16) return bf2f(((const __hip_bfloat16*)p)[i]);
  else      return ((const float*)p)[i];
}
template <bool BF16>
__device__ __forceinline__ void stout(void* p, size_t i, float v) {
  if (BF16) ((__hip_bfloat16*)p)[i] = __float2bfloat16(v);
  else      ((float*)p)[i] = v;
}

__device__ __forceinline__ float bflo(unsigned u) { return __uint_as_float(u << 16); }
__device__ __forceinline__ float bfhi(unsigned u) { return __uint_as_float(u & 0xffff0000u); }

// pack two f32 -> packed bf16x2 (lo in low16, hi in high16)
__device__ __forceinline__ unsigned pack_bf16(float lo, float hi) {
#if __has_builtin(__builtin_amdgcn_cvt_pk_bf16_f32)
  typedef __attribute__((ext_vector_type(2))) __bf16 b2t;
  b2t r = __builtin_amdgcn_cvt_pk_bf16_f32(lo, hi);
  unsigned u; __builtin_memcpy(&u, &r, 4); return u;
#else
  unsigned ul = __float_as_uint(lo) + 0x8000u;   // round-half-up
  unsigned uh = __float_as_uint(hi) + 0x8000u;
  return __builtin_amdgcn_perm(uh, ul, 0x07060302);
#endif
}

// Detect input dtype: bf16 ray-direction norms are ~1; f32 misread as bf16 is garbage.
__global__ void detect_kernel(const void* __restrict__ rdv, float* __restrict__ ws) {
  int lane = threadIdx.x;  // 64 threads
  const __hip_bfloat16* p = (const __hip_bfloat16*)rdv;
  float x = bf2f(p[lane * 3 + 0]);
  float y = bf2f(p[lane * 3 + 1]);
  float z = bf2f(p[lane * 3 + 2]);
  float n2 = x * x + y * y + z * z;
  bool ok = (n2 > 0.95f) && (n2 < 1.05f);
  unsigned long long m = __ballot(ok);
  if (lane == 0) *((int*)((char*)ws + WSB_FLAG)) = (m == ~0ull) ? 1 : 0;
}

// W1 [240][64] -> swizzled bf16 in exact MFMA B-frag read order:
// dst[((cc*4+nb)*64 + lane)*8 + j] = W1[k= 32cc+8*(lane>>4)+j][n= nb*16+(lane&15)]
template <bool BF16>
__global__ void prep_kernel(const void* __restrict__ W1,
                            const void* __restrict__ b1,
                            const void* __restrict__ W2,
                            const void* __restrict__ b2,
                            float* __restrict__ ws) {
  if ((*((const int*)((char*)ws + WSB_FLAG)) != 0) != BF16) return;
  int tid = blockIdx.x * blockDim.x + threadIdx.x;  // 64*256 = 16384
  unsigned short* w1sw = (unsigned short*)((char*)ws + WSB_W1S);
  if (tid < 16384) {
    int j    = tid & 7;
    int lane = (tid >> 3) & 63;
    int nb   = (tid >> 9) & 3;
    int cc   = tid >> 11;
    int quad = lane >> 4, l15 = lane & 15;
    int k = 32 * cc + 8 * quad + j;
    int n = nb * 16 + l15;
    float v = (k < 240) ? ldin<BF16>(W1, (size_t)k * 64 + n) : 0.0f;
    w1sw[tid] = (unsigned short)f2bs(v);
  }
  float* w2f = (float*)((char*)ws + WSB_W2);
  float* b1f = (float*)((char*)ws + WSB_B1);
  float* b2f = (float*)((char*)ws + WSB_B2);
  if (tid < 256) w2f[tid] = ldin<BF16>(W2, tid);
  if (tid < 64)  b1f[tid] = ldin<BF16>(b1, tid);
  if (tid < 4)   b2f[tid] = ldin<BF16>(b2, tid);
}

// planes[p][c][y][x] -> planesT[p][y*64+x][80] (bf16, channel-last)
template <bool BF16>
__global__ void transpose_kernel(const void* __restrict__ planes, float* __restrict__ ws) {
  if ((*((const int*)((char*)ws + WSB_FLAG)) != 0) != BF16) return;
  int tid = blockIdx.x * blockDim.x + threadIdx.x;
  if (tid >= 3 * 4096 * 80) return;
  int c   = tid % 80;
  int tex = (tid / 80) & 4095;
  int p   = tid / (80 * 4096);
  unsigned short* ptb = (unsigned short*)((char*)ws + WSB_PT);
  float v = ldin<BF16>(planes, ((size_t)(p * 80 + c) * 4096) + tex);
  ptb[tid] = (unsigned short)f2bs(v);
}

struct TapInfo {
  float w00, w10, w01, w11;
  int o00, o10, o01, o11;   // texel indices (y*64+x)
};
__device__ __forceinline__ TapInfo tap_setup(float u, float v) {
  TapInfo t;
  float fx = u * 32.0f + 31.5f;
  float fy = v * 32.0f + 31.5f;
  float flx = floorf(fx), fly = floorf(fy);
  int x0 = (int)flx, y0 = (int)fly;
  float wx = fx - flx, wy = fy - fly;
  int x1 = x0 + 1, y1 = y0 + 1;
  bool vx0 = (x0 >= 0) && (x0 < 64);
  bool vx1 = (x1 >= 0) && (x1 < 64);
  bool vy0 = (y0 >= 0) && (y0 < 64);
  bool vy1 = (y1 >= 0) && (y1 < 64);
  int cx0 = min(max(x0, 0), 63), cx1 = min(max(x1, 0), 63);
  int cy0 = min(max(y0, 0), 63), cy1 = min(max(y1, 0), 63);
  t.w00 = (1.0f - wx) * (1.0f - wy) * ((vx0 && vy0) ? 1.0f : 0.0f);
  t.w10 = wx * (1.0f - wy)          * ((vx1 && vy0) ? 1.0f : 0.0f);
  t.w01 = (1.0f - wx) * wy          * ((vx0 && vy1) ? 1.0f : 0.0f);
  t.w11 = wx * wy                   * ((vx1 && vy1) ? 1.0f : 0.0f);
  t.o00 = cy0 * 64 + cx0; t.o10 = cy0 * 64 + cx1;
  t.o01 = cy1 * 64 + cx0; t.o11 = cy1 * 64 + cx1;
  return t;
}

#define SEL3(pl, a, b, c) ((pl) == 0 ? (a) : ((pl) == 1 ? (b) : (c)))

// Block = 1 ray: 4 waves x 6 iterations x (4 samples x 4 decodes = 16 MFMA rows).
template <bool BF16>
__global__ __launch_bounds__(256, 4) void fused_kernel(
    const void* __restrict__ ro,
    const void* __restrict__ rd,
    const float* __restrict__ ws,
    void* __restrict__ out) {
  if ((*((const int*)((const char*)ws + WSB_FLAG)) != 0) != BF16) return;

  __shared__ __align__(16) unsigned short w1s[16384];  // 32 KB, MFMA-read order
  __shared__ float rec[S_PER][8];
  __shared__ float scanb[S_PER];
  __shared__ float w2s[256];
  __shared__ float b1s[64];

  const unsigned short* ptb = (const unsigned short*)((const char*)ws + WSB_PT);
  const float* w2f = (const float*)((const char*)ws + WSB_W2);
  const float* b1f = (const float*)((const char*)ws + WSB_B1);
  const float* b2f = (const float*)((const char*)ws + WSB_B2);

  int tid = threadIdx.x;
  int wave = tid >> 6;
  int lane = tid & 63;
  int lane15 = lane & 15;
  int quad = lane >> 4;
  int ray = blockIdx.x;

  // stage swizzled W1 (linear 32KB), W2, b1 into LDS
  {
    const uint4* src = (const uint4*)((const char*)ws + WSB_W1S);
    uint4* dst = (uint4*)w1s;
    #pragma unroll
    for (int t = 0; t < 8; t++) dst[tid + 256 * t] = src[tid + 256 * t];
  }
  if (tid < 256) w2s[tid] = w2f[tid];
  if (tid < 64)  b1s[tid] = b1f[tid];

  // ray data (uniform across block)
  float ox = ldin<BF16>(ro, (size_t)ray*3+0), oy = ldin<BF16>(ro, (size_t)ray*3+1), oz = ldin<BF16>(ro, (size_t)ray*3+2);
  float dx = ldin<BF16>(rd, (size_t)ray*3+0), dy = ldin<BF16>(rd, (size_t)ray*3+1), dz = ldin<BF16>(rd, (size_t)ray*3+2);
  float o3[3] = {ox, oy, oz}, d3[3] = {dx, dy, dz};
  float tmin = -1e30f, tmax = 1e30f;
  #pragma unroll
  for (int k = 0; k < 3; k++) {
    float sd = (fabsf(d3[k]) < 1e-9f) ? 1e-9f : d3[k];
    float ta = (-0.6f - o3[k]) / sd;
    float tb = ( 0.6f - o3[k]) / sd;
    tmin = fmaxf(tmin, fminf(ta, tb));
    tmax = fminf(tmax, fmaxf(ta, tb));
  }
  float tn = fmaxf(tmin, 0.0f);
  float span = fmaxf(tmax - tn, 0.0f);
  float delta = span * (1.0f / (float)S_PER);
  float b2_0 = b2f[0], b2_1 = b2f[1], b2_2 = b2f[2], b2_3 = b2f[3];

  __syncthreads();

  #pragma unroll 1
  for (int it = 0; it < 6; it++) {
    int sbase = it * 16 + wave * 4;

    // ---- feature stage: this lane feeds A-row m = lane15 (sample sF, decode d)
    int sF = sbase + (lane15 >> 2);
    int d  = lane15 & 3;
    float depF = tn + span * (((float)sF + 0.5f) * (1.0f / (float)S_PER));
    float px = ox + depF * dx, py = oy + depF * dy, pz = oz + depF * dz;
    if (d == 1) px += 0.01f;
    if (d == 2) py += 0.01f;
    if (d == 3) pz += 0.01f;
    if (d > 0) {
      px = fminf(fmaxf(px, -0.6f), 0.6f);
      py = fminf(fmaxf(py, -0.6f), 0.6f);
      pz = fminf(fmaxf(pz, -0.6f), 0.6f);
    }
    const float inv = 1.0f / 0.6f;
    float ux = px * inv, uy = py * inv, uz = pz * inv;
    TapInfo t0 = tap_setup(ux, uy);   // plane 0: (x,y)
    TapInfo t1 = tap_setup(ux, uz);   // plane 1: (x,z)
    TapInfo t2 = tap_setup(uy, uz);   // plane 2: (y,z)
    int p0b00 = t0.o00 * 80,          p0b10 = t0.o10 * 80,          p0b01 = t0.o01 * 80,          p0b11 = t0.o11 * 80;
    int p1b00 = (4096 + t1.o00) * 80, p1b10 = (4096 + t1.o10) * 80, p1b01 = (4096 + t1.o01) * 80, p1b11 = (4096 + t1.o11) * 80;
    int p2b00 = (8192 + t2.o00) * 80, p2b10 = (8192 + t2.o10) * 80, p2b01 = (8192 + t2.o01) * 80, p2b11 = (8192 + t2.o11) * 80;

    f32x4 acc[4];
    #pragma unroll
    for (int nb = 0; nb < 4; nb++) acc[nb] = (f32x4){0.f, 0.f, 0.f, 0.f};

    #pragma unroll
    for (int cc = 0; cc < 8; cc++) {
      int kb = 32 * cc + 8 * quad;
      int4 afi = {0, 0, 0, 0};
      if (kb < 240) {
        int pl = (kb >= 160) ? 2 : ((kb >= 80) ? 1 : 0);
        int ch = kb - pl * 80;
        int a00 = SEL3(pl, p0b00, p1b00, p2b00) + ch;
        int a10 = SEL3(pl, p0b10, p1b10, p2b10) + ch;
        int a01 = SEL3(pl, p0b01, p1b01, p2b01) + ch;
        int a11 = SEL3(pl, p0b11, p1b11, p2b11) + ch;
        float w00 = SEL3(pl, t0.w00, t1.w00, t2.w00);
        float w10 = SEL3(pl, t0.w10, t1.w10, t2.w10);
        float w01 = SEL3(pl, t0.w01, t1.w01, t2.w01);
        float w11 = SEL3(pl, t0.w11, t1.w11, t2.w11);
        uint4 q00 = *(const uint4*)(ptb + a00);
        uint4 q10 = *(const uint4*)(ptb + a10);
        uint4 q01 = *(const uint4*)(ptb + a01);
        uint4 q11 = *(const uint4*)(ptb + a11);
        unsigned u00[4] = {q00.x, q00.y, q00.z, q00.w};
        unsigned u10[4] = {q10.x, q10.y, q10.z, q10.w};
        unsigned u01[4] = {q01.x, q01.y, q01.z, q01.w};
        unsigned u11[4] = {q11.x, q11.y, q11.z, q11.w};
        int ae[4];
        #pragma unroll
        for (int q = 0; q < 4; q++) {
          float flo = w00 * bflo(u00[q]) + w10 * bflo(u10[q]) + w01 * bflo(u01[q]) + w11 * bflo(u11[q]);
          float fhi = w00 * bfhi(u00[q]) + w10 * bfhi(u10[q]) + w01 * bfhi(u01[q]) + w11 * bfhi(u11[q]);
          ae[q] = (int)pack_bf16(flo, fhi);
        }
        afi.x = ae[0]; afi.y = ae[1]; afi.z = ae[2]; afi.w = ae[3];
      }
      short8 afr;
      __builtin_memcpy(&afr, &afi, 16);
      #pragma unroll
      for (int nb = 0; nb < 4; nb++) {
        short8 bfr = *(const short8*)(w1s + (((cc << 2) | nb) * 64 + lane) * 8);
        acc[nb] = __builtin_amdgcn_mfma_f32_16x16x32_bf16(afr, bfr, acc[nb], 0, 0, 0);
      }
    }

    // ---- layer 2: lane holds h[m=quad*4+reg][n=nb*16+lane15]; d == reg.
    // Need: vals[0..3] = out0 (sdf) for reg 0..3; vals[4..6] = rgb-raw for reg 0.
    float4 w2r[4]; float b1x[4];
    #pragma unroll
    for (int nb = 0; nb < 4; nb++) {
      w2r[nb] = *(const float4*)(w2s + (nb * 16 + lane15) * 4);
      b1x[nb] = b1s[nb * 16 + lane15];
    }
    float vals[7];
    #pragma unroll
    for (int k = 0; k < 7; k++) vals[k] = 0.0f;
    #pragma unroll
    for (int nb = 0; nb < 4; nb++) {
      float hr0 = fmaxf(acc[nb][0] + b1x[nb], 0.0f);
      vals[0] = fmaf(hr0, w2r[nb].x, vals[0]);
      vals[4] = fmaf(hr0, w2r[nb].y, vals[4]);
      vals[5] = fmaf(hr0, w2r[nb].z, vals[5]);
      vals[6] = fmaf(hr0, w2r[nb].w, vals[6]);
      float hr1 = fmaxf(acc[nb][1] + b1x[nb], 0.0f);
      float hr2 = fmaxf(acc[nb][2] + b1x[nb], 0.0f);
      float hr3 = fmaxf(acc[nb][3] + b1x[nb], 0.0f);
      vals[1] = fmaf(hr1, w2r[nb].x, vals[1]);
      vals[2] = fmaf(hr2, w2r[nb].x, vals[2]);
      vals[3] = fmaf(hr3, w2r[nb].x, vals[3]);
    }
    #pragma unroll
    for (int mask = 1; mask < 16; mask <<= 1) {
      #pragma unroll
      for (int k = 0; k < 7; k++) vals[k] += __shfl_xor(vals[k], mask, 64);
    }

    // ---- epilogue: this lane's quad owns sample sE
    int sE = sbase + quad;
    float sdf0 = vals[0] + b2_0;
    float g0 = (vals[1] - vals[0]) * 100.0f;
    float g1 = (vals[2] - vals[0]) * 100.0f;
    float g2 = (vals[3] - vals[0]) * 100.0f;
    float cr = 1.0f / (1.0f + expf(-(vals[4] + b2_1))) * 1.002f - 0.001f;
    float cg = 1.0f / (1.0f + expf(-(vals[5] + b2_2))) * 1.002f - 0.001f;
    float cb = 1.0f / (1.0f + expf(-(vals[6] + b2_3))) * 1.002f - 0.001f;
    float depE = tn + span * (((float)sE + 0.5f) * (1.0f / (float)S_PER));
    float ex = ox + depE * dx, ey = oy + depE * dy, ez = oz + depE * dz;
    float pn = sqrtf(ex * ex + ey * ey + ez * ez);
    // alpha
    float shifted = sdf0 + pn - 0.5f;
    float xarg = -shifted * 80.0f;
    float sigma = (xarg > 20.0f) ? xarg : log1pf(expf(xarg));
    float alpha = 1.0f - expf(-sigma * delta);
    // normalized gradient
    float gl = sqrtf(g0 * g0 + g1 * g1 + g2 * g2) + 1e-8f;
    float igl = 1.0f / gl;

    if (lane15 == 0) {
      rec[sE][0] = alpha;
      rec[sE][1] = cr; rec[sE][2] = cg; rec[sE][3] = cb;
      rec[sE][4] = g0 * igl; rec[sE][5] = g1 * igl; rec[sE][6] = g2 * igl;
      rec[sE][7] = depE;
      size_t gid = (size_t)ray * S_PER + sE;
      stout<BF16>(out, (size_t)32768 + gid * 3 + 0, g0);
      stout<BF16>(out, (size_t)32768 + gid * 3 + 1, g1);
      stout<BF16>(out, (size_t)32768 + gid * 3 + 2, g2);
    }
  }

  __syncthreads();

  // ---- parallel composite: log-space scan for transmittance, tree reduction
  float a = 0.f, l = 0.f, pcr = 0.f, pcg = 0.f, pcb = 0.f, pnx = 0.f, pny = 0.f, pnz = 0.f, pdt = 0.f;
  if (tid < S_PER) {
    a = rec[tid][0];
    l = logf(1.0f - a + 1e-10f);
    pcr = rec[tid][1]; pcg = rec[tid][2]; pcb = rec[tid][3];
    pnx = rec[tid][4]; pny = rec[tid][5]; pnz = rec[tid][6];
    pdt = rec[tid][7];
    scanb[tid] = l;
  }
  __syncthreads();
  #pragma unroll
  for (int st = 1; st < S_PER; st <<= 1) {
    float v = 0.0f;
    if (tid < S_PER && tid >= st) v = scanb[tid - st];
    __syncthreads();
    if (tid < S_PER) scanb[tid] += v;
    __syncthreads();
  }
  if (tid < S_PER) {
    float T = expf(scanb[tid] - l);   // exclusive prefix -> transmittance
    float w = a * T;
    rec[tid][0] = w;
    rec[tid][1] = w * pcr; rec[tid][2] = w * pcg; rec[tid][3] = w * pcb;
    rec[tid][4] = w * pnx; rec[tid][5] = w * pny; rec[tid][6] = w * pnz;
    rec[tid][7] = w * pdt;
  }
  __syncthreads();
  #pragma unroll
  for (int off = 48; off >= 3; off >>= 1) {   // 48,24,12,6,3
    if (tid < off) {
      #pragma unroll
      for (int k = 0; k < 8; k++) rec[tid][k] += rec[tid + off][k];
    }
    __syncthreads();
  }
  if (tid == 0) {
    float R[8];
    #pragma unroll
    for (int k = 0; k < 8; k++) R[k] = rec[0][k] + rec[1][k] + rec[2][k];
    float wsum = R[0];
    float nl = sqrtf(R[4] * R[4] + R[5] * R[5] + R[6] * R[6]) + 1e-8f;
    float inl = 1.0f / nl;
    float nrm3[3] = {R[4], R[5], R[6]};
    float rgb3[3] = {R[1], R[2], R[3]};
    #pragma unroll
    for (int c = 0; c < 3; c++) {
      float n = (nrm3[c] * inl + 1.0f) * 0.5f * wsum;
      stout<BF16>(out, (size_t)(c * 4096 + ray), rgb3[c] + 1.0f - wsum);
      stout<BF16>(out, (size_t)(20480 + c * 4096 + ray), n);
    }
    stout<BF16>(out, (size_t)(12288 + ray), R[7]);
    stout<BF16>(out, (size_t)(16384 + ray), wsum);
  }
}

extern "C" void kernel_launch(void* const* d_in, const int* in_sizes, int n_in,
                              void* d_out, int out_size, void* d_ws, size_t ws_size,
                              hipStream_t stream) {
  const void* planes = d_in[0];
  const void* ro     = d_in[1];
  const void* rd     = d_in[2];
  const void* W1     = d_in[3];
  const void* b1     = d_in[4];
  const void* W2     = d_in[5];
  const void* b2     = d_in[6];
  float* ws = (float*)d_ws;

  detect_kernel<<<1, 64, 0, stream>>>(rd, ws);
  prep_kernel<false><<<64, 256, 0, stream>>>(W1, b1, W2, b2, ws);
  prep_kernel<true ><<<64, 256, 0, stream>>>(W1, b1, W2, b2, ws);
  transpose_kernel<false><<<3840, 256, 0, stream>>>(planes, ws);
  transpose_kernel<true ><<<3840, 256, 0, stream>>>(planes, ws);
  fused_kernel<false><<<NUM_RAYS, 256, 0, stream>>>(ro, rd, ws, d_out);
  fused_kernel<true ><<<NUM_RAYS, 256, 0, stream>>>(ro, rd, ws, d_out);
}

// Round 7
// 548.070 us; speedup vs baseline: 4.2201x; 1.1181x over previous
//
#include <hip/hip_runtime.h>
#include <hip/hip_bf16.h>

#define NUM_RAYS 4096
#define S_PER 96
#define NPTS (NUM_RAYS * S_PER)
#define CCH 80
#define HID 64

// ws layout (byte offsets)
#define WSB_FLAG   0         // int
#define WSB_W2     256       // 256 f32 (64x4)
#define WSB_B1     1536      // 64 f32
#define WSB_B2     1856      // 4 f32
#define WSB_W1S    4096      // 16384 bf16 shorts, swizzled [cc][nb][lane][8]
#define WSB_PT     40960     // 983040 bf16: planesT [p][y*64+x][80]

// d_out layout (elements of output dtype):
// [0) comp_rgb 3*4096 | [12288) depth 4096 | [16384) opacity 4096
// [20480) comp_normal 3*4096 | [32768) sdf_grad 393216*3

typedef __attribute__((ext_vector_type(8))) short short8;
typedef __attribute__((ext_vector_type(4))) float f32x4;

__device__ __forceinline__ float bf2f(__hip_bfloat16 v) { return __bfloat162float(v); }

__device__ __forceinline__ short f2bs(float f) {
  __hip_bfloat16 h = __float2bfloat16(f);
  short s; __builtin_memcpy(&s, &h, 2); return s;
}

template <bool BF16>
__device__ __forceinline__ float ldin(const void* p, size_t i) {
  if (BF16) return bf2f(((const __hip_bfloat16*)p)[i]);
  else      return ((const float*)p)[i];
}
template <bool BF16>
__device__ __forceinline__ void stout(void* p, size_t i, float v) {
  if (BF16) ((__hip_bfloat16*)p)[i] = __float2bfloat16(v);
  else      ((float*)p)[i] = v;
}

__device__ __forceinline__ float bflo(unsigned u) { return __uint_as_float(u << 16); }
__device__ __forceinline__ float bfhi(unsigned u) { return __uint_as_float(u & 0xffff0000u); }

// pack two f32 -> packed bf16x2 (lo in low16, hi in high16)
__device__ __forceinline__ unsigned pack_bf16(float lo, float hi) {
#if __has_builtin(__builtin_amdgcn_cvt_pk_bf16_f32)
  typedef __attribute__((ext_vector_type(2))) __bf16 b2t;
  b2t r = __builtin_amdgcn_cvt_pk_bf16_f32(lo, hi);
  unsigned u; __builtin_memcpy(&u, &r, 4); return u;
#else
  unsigned ul = __float_as_uint(lo) + 0x8000u;   // round-half-up
  unsigned uh = __float_as_uint(hi) + 0x8000u;
  return __builtin_amdgcn_perm(uh, ul, 0x07060302);
#endif
}

// Detect input dtype: bf16 ray-direction norms are ~1; f32 misread as bf16 is garbage.
__global__ void detect_kernel(const void* __restrict__ rdv, float* __restrict__ ws) {
  int lane = threadIdx.x;  // 64 threads
  const __hip_bfloat16* p = (const __hip_bfloat16*)rdv;
  float x = bf2f(p[lane * 3 + 0]);
  float y = bf2f(p[lane * 3 + 1]);
  float z = bf2f(p[lane * 3 + 2]);
  float n2 = x * x + y * y + z * z;
  bool ok = (n2 > 0.95f) && (n2 < 1.05f);
  unsigned long long m = __ballot(ok);
  if (lane == 0) *((int*)((char*)ws + WSB_FLAG)) = (m == ~0ull) ? 1 : 0;
}

// W1 [240][64] -> swizzled bf16 in exact MFMA B-frag read order:
// dst[((cc*4+nb)*64 + lane)*8 + j] = W1[k= 32cc+8*(lane>>4)+j][n= nb*16+(lane&15)]
template <bool BF16>
__global__ void prep_kernel(const void* __restrict__ W1,
                            const void* __restrict__ b1,
                            const void* __restrict__ W2,
                            const void* __restrict__ b2,
                            float* __restrict__ ws) {
  if ((*((const int*)((char*)ws + WSB_FLAG)) != 0) != BF16) return;
  int tid = blockIdx.x * blockDim.x + threadIdx.x;  // 64*256 = 16384
  unsigned short* w1sw = (unsigned short*)((char*)ws + WSB_W1S);
  if (tid < 16384) {
    int j    = tid & 7;
    int lane = (tid >> 3) & 63;
    int nb   = (tid >> 9) & 3;
    int cc   = tid >> 11;
    int quad = lane >> 4, l15 = lane & 15;
    int k = 32 * cc + 8 * quad + j;
    int n = nb * 16 + l15;
    float v = (k < 240) ? ldin<BF16>(W1, (size_t)k * 64 + n) : 0.0f;
    w1sw[tid] = (unsigned short)f2bs(v);
  }
  float* w2f = (float*)((char*)ws + WSB_W2);
  float* b1f = (float*)((char*)ws + WSB_B1);
  float* b2f = (float*)((char*)ws + WSB_B2);
  if (tid < 256) w2f[tid] = ldin<BF16>(W2, tid);
  if (tid < 64)  b1f[tid] = ldin<BF16>(b1, tid);
  if (tid < 4)   b2f[tid] = ldin<BF16>(b2, tid);
}

// planes[p][c][y][x] -> planesT[p][y*64+x][80] (bf16, channel-last)
template <bool BF16>
__global__ void transpose_kernel(const void* __restrict__ planes, float* __restrict__ ws) {
  if ((*((const int*)((char*)ws + WSB_FLAG)) != 0) != BF16) return;
  int tid = blockIdx.x * blockDim.x + threadIdx.x;
  if (tid >= 3 * 4096 * 80) return;
  int c   = tid % 80;
  int tex = (tid / 80) & 4095;
  int p   = tid / (80 * 4096);
  unsigned short* ptb = (unsigned short*)((char*)ws + WSB_PT);
  float v = ldin<BF16>(planes, ((size_t)(p * 80 + c) * 4096) + tex);
  ptb[tid] = (unsigned short)f2bs(v);
}

struct TapInfo {
  float w00, w10, w01, w11;
  int o00, o10, o01, o11;   // texel indices (y*64+x)
};
__device__ __forceinline__ TapInfo tap_setup(float u, float v) {
  TapInfo t;
  float fx = u * 32.0f + 31.5f;
  float fy = v * 32.0f + 31.5f;
  float flx = floorf(fx), fly = floorf(fy);
  int x0 = (int)flx, y0 = (int)fly;
  float wx = fx - flx, wy = fy - fly;
  int x1 = x0 + 1, y1 = y0 + 1;
  bool vx0 = (x0 >= 0) && (x0 < 64);
  bool vx1 = (x1 >= 0) && (x1 < 64);
  bool vy0 = (y0 >= 0) && (y0 < 64);
  bool vy1 = (y1 >= 0) && (y1 < 64);
  int cx0 = min(max(x0, 0), 63), cx1 = min(max(x1, 0), 63);
  int cy0 = min(max(y0, 0), 63), cy1 = min(max(y1, 0), 63);
  t.w00 = (1.0f - wx) * (1.0f - wy) * ((vx0 && vy0) ? 1.0f : 0.0f);
  t.w10 = wx * (1.0f - wy)          * ((vx1 && vy0) ? 1.0f : 0.0f);
  t.w01 = (1.0f - wx) * wy          * ((vx0 && vy1) ? 1.0f : 0.0f);
  t.w11 = wx * wy                   * ((vx1 && vy1) ? 1.0f : 0.0f);
  t.o00 = cy0 * 64 + cx0; t.o10 = cy0 * 64 + cx1;
  t.o01 = cy1 * 64 + cx0; t.o11 = cy1 * 64 + cx1;
  return t;
}

#define SEL3(pl, a, b, c) ((pl) == 0 ? (a) : ((pl) == 1 ? (b) : (c)))

// Block = 1 ray: 4 waves x 6 iterations x (4 samples x 4 decodes = 16 MFMA rows).
// launch_bounds(256,3): cap VGPR at ~170 (compiler naturally wants ~168);
// (256,4) forced VGPR=64 -> 1.9 GB/launch scratch spill (R6 post-mortem).
template <bool BF16>
__global__ __launch_bounds__(256, 3) void fused_kernel(
    const void* __restrict__ ro,
    const void* __restrict__ rd,
    const float* __restrict__ ws,
    void* __restrict__ out) {
  if ((*((const int*)((const char*)ws + WSB_FLAG)) != 0) != BF16) return;

  __shared__ __align__(16) unsigned short w1s[16384];  // 32 KB, MFMA-read order
  __shared__ float rec[S_PER][8];
  __shared__ float scanb[S_PER];
  __shared__ float w2s[256];
  __shared__ float b1s[64];

  const unsigned short* ptb = (const unsigned short*)((const char*)ws + WSB_PT);
  const float* w2f = (const float*)((const char*)ws + WSB_W2);
  const float* b1f = (const float*)((const char*)ws + WSB_B1);
  const float* b2f = (const float*)((const char*)ws + WSB_B2);

  int tid = threadIdx.x;
  int wave = tid >> 6;
  int lane = tid & 63;
  int lane15 = lane & 15;
  int quad = lane >> 4;
  int ray = blockIdx.x;

  // stage swizzled W1 (linear 32KB), W2, b1 into LDS
  {
    const uint4* src = (const uint4*)((const char*)ws + WSB_W1S);
    uint4* dst = (uint4*)w1s;
    #pragma unroll
    for (int t = 0; t < 8; t++) dst[tid + 256 * t] = src[tid + 256 * t];
  }
  if (tid < 256) w2s[tid] = w2f[tid];
  if (tid < 64)  b1s[tid] = b1f[tid];

  // ray data (uniform across block)
  float ox = ldin<BF16>(ro, (size_t)ray*3+0), oy = ldin<BF16>(ro, (size_t)ray*3+1), oz = ldin<BF16>(ro, (size_t)ray*3+2);
  float dx = ldin<BF16>(rd, (size_t)ray*3+0), dy = ldin<BF16>(rd, (size_t)ray*3+1), dz = ldin<BF16>(rd, (size_t)ray*3+2);
  float o3[3] = {ox, oy, oz}, d3[3] = {dx, dy, dz};
  float tmin = -1e30f, tmax = 1e30f;
  #pragma unroll
  for (int k = 0; k < 3; k++) {
    float sd = (fabsf(d3[k]) < 1e-9f) ? 1e-9f : d3[k];
    float ta = (-0.6f - o3[k]) / sd;
    float tb = ( 0.6f - o3[k]) / sd;
    tmin = fmaxf(tmin, fminf(ta, tb));
    tmax = fminf(tmax, fmaxf(ta, tb));
  }
  float tn = fmaxf(tmin, 0.0f);
  float span = fmaxf(tmax - tn, 0.0f);
  float delta = span * (1.0f / (float)S_PER);
  float b2_0 = b2f[0], b2_1 = b2f[1], b2_2 = b2f[2], b2_3 = b2f[3];

  __syncthreads();

  #pragma unroll 1
  for (int it = 0; it < 6; it++) {
    int sbase = it * 16 + wave * 4;

    // ---- feature stage: this lane feeds A-row m = lane15 (sample sF, decode d)
    int sF = sbase + (lane15 >> 2);
    int d  = lane15 & 3;
    float depF = tn + span * (((float)sF + 0.5f) * (1.0f / (float)S_PER));
    float px = ox + depF * dx, py = oy + depF * dy, pz = oz + depF * dz;
    if (d == 1) px += 0.01f;
    if (d == 2) py += 0.01f;
    if (d == 3) pz += 0.01f;
    if (d > 0) {
      px = fminf(fmaxf(px, -0.6f), 0.6f);
      py = fminf(fmaxf(py, -0.6f), 0.6f);
      pz = fminf(fmaxf(pz, -0.6f), 0.6f);
    }
    const float inv = 1.0f / 0.6f;
    float ux = px * inv, uy = py * inv, uz = pz * inv;
    TapInfo t0 = tap_setup(ux, uy);   // plane 0: (x,y)
    TapInfo t1 = tap_setup(ux, uz);   // plane 1: (x,z)
    TapInfo t2 = tap_setup(uy, uz);   // plane 2: (y,z)
    int p0b00 = t0.o00 * 80,          p0b10 = t0.o10 * 80,          p0b01 = t0.o01 * 80,          p0b11 = t0.o11 * 80;
    int p1b00 = (4096 + t1.o00) * 80, p1b10 = (4096 + t1.o10) * 80, p1b01 = (4096 + t1.o01) * 80, p1b11 = (4096 + t1.o11) * 80;
    int p2b00 = (8192 + t2.o00) * 80, p2b10 = (8192 + t2.o10) * 80, p2b01 = (8192 + t2.o01) * 80, p2b11 = (8192 + t2.o11) * 80;

    f32x4 acc[4];
    #pragma unroll
    for (int nb = 0; nb < 4; nb++) acc[nb] = (f32x4){0.f, 0.f, 0.f, 0.f};

    #pragma unroll
    for (int cc = 0; cc < 8; cc++) {
      int kb = 32 * cc + 8 * quad;
      int4 afi = {0, 0, 0, 0};
      if (kb < 240) {
        int pl = (kb >= 160) ? 2 : ((kb >= 80) ? 1 : 0);
        int ch = kb - pl * 80;
        int a00 = SEL3(pl, p0b00, p1b00, p2b00) + ch;
        int a10 = SEL3(pl, p0b10, p1b10, p2b10) + ch;
        int a01 = SEL3(pl, p0b01, p1b01, p2b01) + ch;
        int a11 = SEL3(pl, p0b11, p1b11, p2b11) + ch;
        float w00 = SEL3(pl, t0.w00, t1.w00, t2.w00);
        float w10 = SEL3(pl, t0.w10, t1.w10, t2.w10);
        float w01 = SEL3(pl, t0.w01, t1.w01, t2.w01);
        float w11 = SEL3(pl, t0.w11, t1.w11, t2.w11);
        uint4 q00 = *(const uint4*)(ptb + a00);
        uint4 q10 = *(const uint4*)(ptb + a10);
        uint4 q01 = *(const uint4*)(ptb + a01);
        uint4 q11 = *(const uint4*)(ptb + a11);
        unsigned u00[4] = {q00.x, q00.y, q00.z, q00.w};
        unsigned u10[4] = {q10.x, q10.y, q10.z, q10.w};
        unsigned u01[4] = {q01.x, q01.y, q01.z, q01.w};
        unsigned u11[4] = {q11.x, q11.y, q11.z, q11.w};
        int ae[4];
        #pragma unroll
        for (int q = 0; q < 4; q++) {
          float flo = w00 * bflo(u00[q]) + w10 * bflo(u10[q]) + w01 * bflo(u01[q]) + w11 * bflo(u11[q]);
          float fhi = w00 * bfhi(u00[q]) + w10 * bfhi(u10[q]) + w01 * bfhi(u01[q]) + w11 * bfhi(u11[q]);
          ae[q] = (int)pack_bf16(flo, fhi);
        }
        afi.x = ae[0]; afi.y = ae[1]; afi.z = ae[2]; afi.w = ae[3];
      }
      short8 afr;
      __builtin_memcpy(&afr, &afi, 16);
      #pragma unroll
      for (int nb = 0; nb < 4; nb++) {
        short8 bfr = *(const short8*)(w1s + (((cc << 2) | nb) * 64 + lane) * 8);
        acc[nb] = __builtin_amdgcn_mfma_f32_16x16x32_bf16(afr, bfr, acc[nb], 0, 0, 0);
      }
    }

    // ---- layer 2: lane holds h[m=quad*4+reg][n=nb*16+lane15]; d == reg.
    float4 w2r[4]; float b1x[4];
    #pragma unroll
    for (int nb = 0; nb < 4; nb++) {
      w2r[nb] = *(const float4*)(w2s + (nb * 16 + lane15) * 4);
      b1x[nb] = b1s[nb * 16 + lane15];
    }
    float vals[7];
    #pragma unroll
    for (int k = 0; k < 7; k++) vals[k] = 0.0f;
    #pragma unroll
    for (int nb = 0; nb < 4; nb++) {
      float hr0 = fmaxf(acc[nb][0] + b1x[nb], 0.0f);
      vals[0] = fmaf(hr0, w2r[nb].x, vals[0]);
      vals[4] = fmaf(hr0, w2r[nb].y, vals[4]);
      vals[5] = fmaf(hr0, w2r[nb].z, vals[5]);
      vals[6] = fmaf(hr0, w2r[nb].w, vals[6]);
      float hr1 = fmaxf(acc[nb][1] + b1x[nb], 0.0f);
      float hr2 = fmaxf(acc[nb][2] + b1x[nb], 0.0f);
      float hr3 = fmaxf(acc[nb][3] + b1x[nb], 0.0f);
      vals[1] = fmaf(hr1, w2r[nb].x, vals[1]);
      vals[2] = fmaf(hr2, w2r[nb].x, vals[2]);
      vals[3] = fmaf(hr3, w2r[nb].x, vals[3]);
    }
    #pragma unroll
    for (int mask = 1; mask < 16; mask <<= 1) {
      #pragma unroll
      for (int k = 0; k < 7; k++) vals[k] += __shfl_xor(vals[k], mask, 64);
    }

    // ---- epilogue: this lane's quad owns sample sE
    int sE = sbase + quad;
    float sdf0 = vals[0] + b2_0;
    float g0 = (vals[1] - vals[0]) * 100.0f;
    float g1 = (vals[2] - vals[0]) * 100.0f;
    float g2 = (vals[3] - vals[0]) * 100.0f;
    float cr = 1.0f / (1.0f + expf(-(vals[4] + b2_1))) * 1.002f - 0.001f;
    float cg = 1.0f / (1.0f + expf(-(vals[5] + b2_2))) * 1.002f - 0.001f;
    float cb = 1.0f / (1.0f + expf(-(vals[6] + b2_3))) * 1.002f - 0.001f;
    float depE = tn + span * (((float)sE + 0.5f) * (1.0f / (float)S_PER));
    float ex = ox + depE * dx, ey = oy + depE * dy, ez = oz + depE * dz;
    float pn = sqrtf(ex * ex + ey * ey + ez * ez);
    // alpha
    float shifted = sdf0 + pn - 0.5f;
    float xarg = -shifted * 80.0f;
    float sigma = (xarg > 20.0f) ? xarg : log1pf(expf(xarg));
    float alpha = 1.0f - expf(-sigma * delta);
    // normalized gradient
    float gl = sqrtf(g0 * g0 + g1 * g1 + g2 * g2) + 1e-8f;
    float igl = 1.0f / gl;

    if (lane15 == 0) {
      rec[sE][0] = alpha;
      rec[sE][1] = cr; rec[sE][2] = cg; rec[sE][3] = cb;
      rec[sE][4] = g0 * igl; rec[sE][5] = g1 * igl; rec[sE][6] = g2 * igl;
      rec[sE][7] = depE;
      size_t gid = (size_t)ray * S_PER + sE;
      stout<BF16>(out, (size_t)32768 + gid * 3 + 0, g0);
      stout<BF16>(out, (size_t)32768 + gid * 3 + 1, g1);
      stout<BF16>(out, (size_t)32768 + gid * 3 + 2, g2);
    }
  }

  __syncthreads();

  // ---- parallel composite: log-space scan for transmittance, tree reduction
  float a = 0.f, l = 0.f, pcr = 0.f, pcg = 0.f, pcb = 0.f, pnx = 0.f, pny = 0.f, pnz = 0.f, pdt = 0.f;
  if (tid < S_PER) {
    a = rec[tid][0];
    l = logf(1.0f - a + 1e-10f);
    pcr = rec[tid][1]; pcg = rec[tid][2]; pcb = rec[tid][3];
    pnx = rec[tid][4]; pny = rec[tid][5]; pnz = rec[tid][6];
    pdt = rec[tid][7];
    scanb[tid] = l;
  }
  __syncthreads();
  #pragma unroll
  for (int st = 1; st < S_PER; st <<= 1) {
    float v = 0.0f;
    if (tid < S_PER && tid >= st) v = scanb[tid - st];
    __syncthreads();
    if (tid < S_PER) scanb[tid] += v;
    __syncthreads();
  }
  if (tid < S_PER) {
    float T = expf(scanb[tid] - l);   // exclusive prefix -> transmittance
    float w = a * T;
    rec[tid][0] = w;
    rec[tid][1] = w * pcr; rec[tid][2] = w * pcg; rec[tid][3] = w * pcb;
    rec[tid][4] = w * pnx; rec[tid][5] = w * pny; rec[tid][6] = w * pnz;
    rec[tid][7] = w * pdt;
  }
  __syncthreads();
  #pragma unroll
  for (int off = 48; off >= 3; off >>= 1) {   // 48,24,12,6,3
    if (tid < off) {
      #pragma unroll
      for (int k = 0; k < 8; k++) rec[tid][k] += rec[tid + off][k];
    }
    __syncthreads();
  }
  if (tid == 0) {
    float R[8];
    #pragma unroll
    for (int k = 0; k < 8; k++) R[k] = rec[0][k] + rec[1][k] + rec[2][k];
    float wsum = R[0];
    float nl = sqrtf(R[4] * R[4] + R[5] * R[5] + R[6] * R[6]) + 1e-8f;
    float inl = 1.0f / nl;
    float nrm3[3] = {R[4], R[5], R[6]};
    float rgb3[3] = {R[1], R[2], R[3]};
    #pragma unroll
    for (int c = 0; c < 3; c++) {
      float n = (nrm3[c] * inl + 1.0f) * 0.5f * wsum;
      stout<BF16>(out, (size_t)(c * 4096 + ray), rgb3[c] + 1.0f - wsum);
      stout<BF16>(out, (size_t)(20480 + c * 4096 + ray), n);
    }
    stout<BF16>(out, (size_t)(12288 + ray), R[7]);
    stout<BF16>(out, (size_t)(16384 + ray), wsum);
  }
}

extern "C" void kernel_launch(void* const* d_in, const int* in_sizes, int n_in,
                              void* d_out, int out_size, void* d_ws, size_t ws_size,
                              hipStream_t stream) {
  const void* planes = d_in[0];
  const void* ro     = d_in[1];
  const void* rd     = d_in[2];
  const void* W1     = d_in[3];
  const void* b1     = d_in[4];
  const void* W2     = d_in[5];
  const void* b2     = d_in[6];
  float* ws = (float*)d_ws;

  detect_kernel<<<1, 64, 0, stream>>>(rd, ws);
  prep_kernel<false><<<64, 256, 0, stream>>>(W1, b1, W2, b2, ws);
  prep_kernel<true ><<<64, 256, 0, stream>>>(W1, b1, W2, b2, ws);
  transpose_kernel<false><<<3840, 256, 0, stream>>>(planes, ws);
  transpose_kernel<true ><<<3840, 256, 0, stream>>>(planes, ws);
  fused_kernel<false><<<NUM_RAYS, 256, 0, stream>>>(ro, rd, ws, d_out);
  fused_kernel<true ><<<NUM_RAYS, 256, 0, stream>>>(ro, rd, ws, d_out);
}

// Round 8
// 333.107 us; speedup vs baseline: 6.9434x; 1.6453x over previous
//
#include <hip/hip_runtime.h>
#include <hip/hip_bf16.h>

#define NUM_RAYS 4096
#define S_PER 96
#define NPTS (NUM_RAYS * S_PER)
#define CCH 80
#define HID 64
#define NCHUNK 9   // 3 planes x 3 K-chunks of 32 (plane K padded 80->96)

// ws layout (byte offsets)
#define WSB_FLAG   0         // int
#define WSB_W2     256       // 256 f32 (64x4)
#define WSB_B1     1536      // 64 f32
#define WSB_B2     1856      // 4 f32
#define WSB_W1S    4096      // 18432 bf16 shorts, swizzled [cc][nb][lane][8], 36864 B
#define WSB_PT     40960     // 983040 bf16: planesT [p][y*64+x][80]

// d_out layout (elements of output dtype):
// [0) comp_rgb 3*4096 | [12288) depth 4096 | [16384) opacity 4096
// [20480) comp_normal 3*4096 | [32768) sdf_grad 393216*3

typedef __attribute__((ext_vector_type(8))) short short8;
typedef __attribute__((ext_vector_type(4))) float f32x4;

__device__ __forceinline__ float bf2f(__hip_bfloat16 v) { return __bfloat162float(v); }

__device__ __forceinline__ short f2bs(float f) {
  __hip_bfloat16 h = __float2bfloat16(f);
  short s; __builtin_memcpy(&s, &h, 2); return s;
}

template <bool BF16>
__device__ __forceinline__ float ldin(const void* p, size_t i) {
  if (BF16) return bf2f(((const __hip_bfloat16*)p)[i]);
  else      return ((const float*)p)[i];
}
template <bool BF16>
__device__ __forceinline__ void stout(void* p, size_t i, float v) {
  if (BF16) ((__hip_bfloat16*)p)[i] = __float2bfloat16(v);
  else      ((float*)p)[i] = v;
}

__device__ __forceinline__ float bflo(unsigned u) { return __uint_as_float(u << 16); }
__device__ __forceinline__ float bfhi(unsigned u) { return __uint_as_float(u & 0xffff0000u); }

// pack two f32 -> packed bf16x2 (lo in low16, hi in high16)
__device__ __forceinline__ unsigned pack_bf16(float lo, float hi) {
#if __has_builtin(__builtin_amdgcn_cvt_pk_bf16_f32)
  typedef __attribute__((ext_vector_type(2))) __bf16 b2t;
  b2t r = __builtin_amdgcn_cvt_pk_bf16_f32(lo, hi);
  unsigned u; __builtin_memcpy(&u, &r, 4); return u;
#else
  unsigned ul = __float_as_uint(lo) + 0x8000u;   // round-half-up
  unsigned uh = __float_as_uint(hi) + 0x8000u;
  return __builtin_amdgcn_perm(uh, ul, 0x07060302);
#endif
}

// Detect input dtype: bf16 ray-direction norms are ~1; f32 misread as bf16 is garbage.
__global__ void detect_kernel(const void* __restrict__ rdv, float* __restrict__ ws) {
  int lane = threadIdx.x;  // 64 threads
  const __hip_bfloat16* p = (const __hip_bfloat16*)rdv;
  float x = bf2f(p[lane * 3 + 0]);
  float y = bf2f(p[lane * 3 + 1]);
  float z = bf2f(p[lane * 3 + 2]);
  float n2 = x * x + y * y + z * z;
  bool ok = (n2 > 0.95f) && (n2 < 1.05f);
  unsigned long long m = __ballot(ok);
  if (lane == 0) *((int*)((char*)ws + WSB_FLAG)) = (m == ~0ull) ? 1 : 0;
}

// W1 [240][64] -> swizzled bf16 in MFMA B-frag read order with per-plane padding:
// chunk cc = p*3+ccl covers plane p, channels ch = ccl*32 + 8*quad + j (0 if ch>=80)
template <bool BF16>
__global__ void prep_kernel(const void* __restrict__ W1,
                            const void* __restrict__ b1,
                            const void* __restrict__ W2,
                            const void* __restrict__ b2,
                            float* __restrict__ ws) {
  if ((*((const int*)((char*)ws + WSB_FLAG)) != 0) != BF16) return;
  int tid = blockIdx.x * blockDim.x + threadIdx.x;
  unsigned short* w1sw = (unsigned short*)((char*)ws + WSB_W1S);
  if (tid < NCHUNK * 4 * 64 * 8) {
    int j    = tid & 7;
    int lane = (tid >> 3) & 63;
    int nb   = (tid >> 9) & 3;
    int cc   = tid >> 11;          // 0..8
    int p    = cc / 3, ccl = cc - 3 * p;
    int quad = lane >> 4, l15 = lane & 15;
    int ch = ccl * 32 + 8 * quad + j;
    int n = nb * 16 + l15;
    float v = (ch < 80) ? ldin<BF16>(W1, (size_t)(p * 80 + ch) * 64 + n) : 0.0f;
    w1sw[tid] = (unsigned short)f2bs(v);
  }
  float* w2f = (float*)((char*)ws + WSB_W2);
  float* b1f = (float*)((char*)ws + WSB_B1);
  float* b2f = (float*)((char*)ws + WSB_B2);
  if (tid < 256) w2f[tid] = ldin<BF16>(W2, tid);
  if (tid < 64)  b1f[tid] = ldin<BF16>(b1, tid);
  if (tid < 4)   b2f[tid] = ldin<BF16>(b2, tid);
}

// planes[p][c][y][x] -> planesT[p][y*64+x][80] (bf16, channel-last).
// Coalesced reads (lanes sweep tex), 32B-contiguous writes (16 channels/thread).
// grid: 3 planes x 5 ctiles x 16 textiles = 240 blocks, 256 threads.
template <bool BF16>
__global__ void transpose_kernel(const void* __restrict__ planes, float* __restrict__ ws) {
  if ((*((const int*)((char*)ws + WSB_FLAG)) != 0) != BF16) return;
  int b  = blockIdx.x;
  int tt = b & 15;
  int ct = (b >> 4) % 5;
  int p  = b / 80;
  int tex = tt * 256 + threadIdx.x;
  unsigned u[8];
  #pragma unroll
  for (int i = 0; i < 8; i++) {
    int c0 = ct * 16 + 2 * i;
    float v0 = ldin<BF16>(planes, ((size_t)(p * 80 + c0) * 4096) + tex);
    float v1 = ldin<BF16>(planes, ((size_t)(p * 80 + c0 + 1) * 4096) + tex);
    unsigned s0 = (unsigned short)f2bs(v0);
    unsigned s1 = (unsigned short)f2bs(v1);
    u[i] = s0 | (s1 << 16);
  }
  unsigned short* ptb = (unsigned short*)((char*)ws + WSB_PT);
  uint4* dst = (uint4*)(ptb + ((size_t)(p * 4096 + tex) * 80 + ct * 16));
  dst[0] = make_uint4(u[0], u[1], u[2], u[3]);
  dst[1] = make_uint4(u[4], u[5], u[6], u[7]);
}

struct TapInfo {
  float w00, w10, w01, w11;
  int o00, o10, o01, o11;   // texel indices (y*64+x)
};
__device__ __forceinline__ TapInfo tap_setup(float u, float v) {
  TapInfo t;
  float fx = u * 32.0f + 31.5f;
  float fy = v * 32.0f + 31.5f;
  float flx = floorf(fx), fly = floorf(fy);
  int x0 = (int)flx, y0 = (int)fly;
  float wx = fx - flx, wy = fy - fly;
  int x1 = x0 + 1, y1 = y0 + 1;
  bool vx0 = (x0 >= 0) && (x0 < 64);
  bool vx1 = (x1 >= 0) && (x1 < 64);
  bool vy0 = (y0 >= 0) && (y0 < 64);
  bool vy1 = (y1 >= 0) && (y1 < 64);
  int cx0 = min(max(x0, 0), 63), cx1 = min(max(x1, 0), 63);
  int cy0 = min(max(y0, 0), 63), cy1 = min(max(y1, 0), 63);
  t.w00 = (1.0f - wx) * (1.0f - wy) * ((vx0 && vy0) ? 1.0f : 0.0f);
  t.w10 = wx * (1.0f - wy)          * ((vx1 && vy0) ? 1.0f : 0.0f);
  t.w01 = (1.0f - wx) * wy          * ((vx0 && vy1) ? 1.0f : 0.0f);
  t.w11 = wx * wy                   * ((vx1 && vy1) ? 1.0f : 0.0f);
  t.o00 = cy0 * 64 + cx0; t.o10 = cy0 * 64 + cx1;
  t.o01 = cy1 * 64 + cx0; t.o11 = cy1 * 64 + cx1;
  return t;
}

// Block = 1 ray: 4 waves x 6 iterations x (4 samples x 4 decodes = 16 MFMA rows).
// K restructured per-plane (pad 80->96) so only ONE TapInfo is live at a time:
// R7 post-mortem showed interleaved-K kept 3 taps + 12 bases live -> scratch spill
// (890 MB FETCH). Plain launch_bounds(256): natural allocation, no spills (R5).
template <bool BF16>
__global__ __launch_bounds__(256) void fused_kernel(
    const void* __restrict__ ro,
    const void* __restrict__ rd,
    const float* __restrict__ ws,
    void* __restrict__ out) {
  if ((*((const int*)((const char*)ws + WSB_FLAG)) != 0) != BF16) return;

  __shared__ __align__(16) unsigned short w1s[NCHUNK * 4 * 64 * 8];  // 36 KB
  __shared__ float rec[S_PER][7];   // alpha, r,g,b, nx,ny,nz
  __shared__ float w2s[256];        // reused as scan buffer in composite

  const unsigned short* ptb = (const unsigned short*)((const char*)ws + WSB_PT);
  const float* w2f = (const float*)((const char*)ws + WSB_W2);
  const float* b1f = (const float*)((const char*)ws + WSB_B1);
  const float* b2f = (const float*)((const char*)ws + WSB_B2);

  int tid = threadIdx.x;
  int wave = tid >> 6;
  int lane = tid & 63;
  int lane15 = lane & 15;
  int quad = lane >> 4;
  int ray = blockIdx.x;

  // stage swizzled W1 (36 KB = 2304 uint4, 9/thread), W2 into LDS
  {
    const uint4* src = (const uint4*)((const char*)ws + WSB_W1S);
    uint4* dst = (uint4*)w1s;
    #pragma unroll
    for (int t = 0; t < 9; t++) dst[tid + 256 * t] = src[tid + 256 * t];
  }
  if (tid < 256) w2s[tid] = w2f[tid];

  // ray data (uniform across block)
  float ox = ldin<BF16>(ro, (size_t)ray*3+0), oy = ldin<BF16>(ro, (size_t)ray*3+1), oz = ldin<BF16>(ro, (size_t)ray*3+2);
  float dx = ldin<BF16>(rd, (size_t)ray*3+0), dy = ldin<BF16>(rd, (size_t)ray*3+1), dz = ldin<BF16>(rd, (size_t)ray*3+2);
  float o3[3] = {ox, oy, oz}, d3[3] = {dx, dy, dz};
  float tmin = -1e30f, tmax = 1e30f;
  #pragma unroll
  for (int k = 0; k < 3; k++) {
    float sd = (fabsf(d3[k]) < 1e-9f) ? 1e-9f : d3[k];
    float ta = (-0.6f - o3[k]) / sd;
    float tb = ( 0.6f - o3[k]) / sd;
    tmin = fmaxf(tmin, fminf(ta, tb));
    tmax = fminf(tmax, fmaxf(ta, tb));
  }
  float tn = fmaxf(tmin, 0.0f);
  float span = fmaxf(tmax - tn, 0.0f);
  float delta = span * (1.0f / (float)S_PER);
  float b2_0 = b2f[0], b2_1 = b2f[1], b2_2 = b2f[2], b2_3 = b2f[3];
  // per-lane b1 (4 VGPRs, replaces LDS b1s)
  float b1x[4];
  #pragma unroll
  for (int nb = 0; nb < 4; nb++) b1x[nb] = b1f[nb * 16 + lane15];

  __syncthreads();

  #pragma unroll 1
  for (int it = 0; it < 6; it++) {
    int sbase = it * 16 + wave * 4;

    // ---- feature stage: this lane feeds A-row m = lane15 (sample sF, decode d)
    int sF = sbase + (lane15 >> 2);
    int d  = lane15 & 3;
    float depF = tn + span * (((float)sF + 0.5f) * (1.0f / (float)S_PER));
    float px = ox + depF * dx, py = oy + depF * dy, pz = oz + depF * dz;
    if (d == 1) px += 0.01f;
    if (d == 2) py += 0.01f;
    if (d == 3) pz += 0.01f;
    if (d > 0) {
      px = fminf(fmaxf(px, -0.6f), 0.6f);
      py = fminf(fmaxf(py, -0.6f), 0.6f);
      pz = fminf(fmaxf(pz, -0.6f), 0.6f);
    }
    const float inv = 1.0f / 0.6f;
    float ux = px * inv, uy = py * inv, uz = pz * inv;

    f32x4 acc[4];
    #pragma unroll
    for (int nb = 0; nb < 4; nb++) acc[nb] = (f32x4){0.f, 0.f, 0.f, 0.f};

    #pragma unroll 1
    for (int p = 0; p < 3; p++) {
      float u = (p == 2) ? uy : ux;
      float v = (p == 0) ? uy : uz;
      TapInfo t = tap_setup(u, v);
      int b00 = (p * 4096 + t.o00) * 80, b10 = (p * 4096 + t.o10) * 80;
      int b01 = (p * 4096 + t.o01) * 80, b11 = (p * 4096 + t.o11) * 80;
      #pragma unroll
      for (int ccl = 0; ccl < 3; ccl++) {
        int ch = ccl * 32 + 8 * quad;
        int4 afi = {0, 0, 0, 0};
        if (ch < 80) {
          uint4 q00 = *(const uint4*)(ptb + b00 + ch);
          uint4 q10 = *(const uint4*)(ptb + b10 + ch);
          uint4 q01 = *(const uint4*)(ptb + b01 + ch);
          uint4 q11 = *(const uint4*)(ptb + b11 + ch);
          unsigned u00[4] = {q00.x, q00.y, q00.z, q00.w};
          unsigned u10[4] = {q10.x, q10.y, q10.z, q10.w};
          unsigned u01[4] = {q01.x, q01.y, q01.z, q01.w};
          unsigned u11[4] = {q11.x, q11.y, q11.z, q11.w};
          int ae[4];
          #pragma unroll
          for (int q = 0; q < 4; q++) {
            float flo = t.w00 * bflo(u00[q]) + t.w10 * bflo(u10[q]) + t.w01 * bflo(u01[q]) + t.w11 * bflo(u11[q]);
            float fhi = t.w00 * bfhi(u00[q]) + t.w10 * bfhi(u10[q]) + t.w01 * bfhi(u01[q]) + t.w11 * bfhi(u11[q]);
            ae[q] = (int)pack_bf16(flo, fhi);
          }
          afi.x = ae[0]; afi.y = ae[1]; afi.z = ae[2]; afi.w = ae[3];
        }
        short8 afr;
        __builtin_memcpy(&afr, &afi, 16);
        int cc = p * 3 + ccl;
        #pragma unroll
        for (int nb = 0; nb < 4; nb++) {
          short8 bfr = *(const short8*)(w1s + (((cc << 2) | nb) * 64 + lane) * 8);
          acc[nb] = __builtin_amdgcn_mfma_f32_16x16x32_bf16(afr, bfr, acc[nb], 0, 0, 0);
        }
      }
    }

    // ---- layer 2: lane holds h[m=quad*4+reg][n=nb*16+lane15]; d == reg.
    float vals[7];
    #pragma unroll
    for (int k = 0; k < 7; k++) vals[k] = 0.0f;
    #pragma unroll
    for (int nb = 0; nb < 4; nb++) {
      float4 w2r = *(const float4*)(w2s + (nb * 16 + lane15) * 4);
      float hr0 = fmaxf(acc[nb][0] + b1x[nb], 0.0f);
      vals[0] = fmaf(hr0, w2r.x, vals[0]);
      vals[4] = fmaf(hr0, w2r.y, vals[4]);
      vals[5] = fmaf(hr0, w2r.z, vals[5]);
      vals[6] = fmaf(hr0, w2r.w, vals[6]);
      float hr1 = fmaxf(acc[nb][1] + b1x[nb], 0.0f);
      float hr2 = fmaxf(acc[nb][2] + b1x[nb], 0.0f);
      float hr3 = fmaxf(acc[nb][3] + b1x[nb], 0.0f);
      vals[1] = fmaf(hr1, w2r.x, vals[1]);
      vals[2] = fmaf(hr2, w2r.x, vals[2]);
      vals[3] = fmaf(hr3, w2r.x, vals[3]);
    }
    #pragma unroll
    for (int mask = 1; mask < 16; mask <<= 1) {
      #pragma unroll
      for (int k = 0; k < 7; k++) vals[k] += __shfl_xor(vals[k], mask, 64);
    }

    // ---- epilogue: this lane's quad owns sample sE
    int sE = sbase + quad;
    float sdf0 = vals[0] + b2_0;
    float g0 = (vals[1] - vals[0]) * 100.0f;
    float g1 = (vals[2] - vals[0]) * 100.0f;
    float g2 = (vals[3] - vals[0]) * 100.0f;
    float cr = 1.0f / (1.0f + expf(-(vals[4] + b2_1))) * 1.002f - 0.001f;
    float cg = 1.0f / (1.0f + expf(-(vals[5] + b2_2))) * 1.002f - 0.001f;
    float cb = 1.0f / (1.0f + expf(-(vals[6] + b2_3))) * 1.002f - 0.001f;
    float depE = tn + span * (((float)sE + 0.5f) * (1.0f / (float)S_PER));
    float ex = ox + depE * dx, ey = oy + depE * dy, ez = oz + depE * dz;
    float pn = sqrtf(ex * ex + ey * ey + ez * ez);
    float shifted = sdf0 + pn - 0.5f;
    float xarg = -shifted * 80.0f;
    float sigma = (xarg > 20.0f) ? xarg : log1pf(expf(xarg));
    float alpha = 1.0f - expf(-sigma * delta);
    float gl = sqrtf(g0 * g0 + g1 * g1 + g2 * g2) + 1e-8f;
    float igl = 1.0f / gl;

    if (lane15 == 0) {
      rec[sE][0] = alpha;
      rec[sE][1] = cr; rec[sE][2] = cg; rec[sE][3] = cb;
      rec[sE][4] = g0 * igl; rec[sE][5] = g1 * igl; rec[sE][6] = g2 * igl;
      size_t gid = (size_t)ray * S_PER + sE;
      stout<BF16>(out, (size_t)32768 + gid * 3 + 0, g0);
      stout<BF16>(out, (size_t)32768 + gid * 3 + 1, g1);
      stout<BF16>(out, (size_t)32768 + gid * 3 + 2, g2);
    }
  }

  __syncthreads();

  // ---- parallel composite: log-space scan for transmittance, tree reduction
  float* scanb = w2s;   // w2s no longer needed
  float a = 0.f, l = 0.f, pcr = 0.f, pcg = 0.f, pcb = 0.f, pnx = 0.f, pny = 0.f, pnz = 0.f, pdt = 0.f;
  if (tid < S_PER) {
    a = rec[tid][0];
    l = logf(1.0f - a + 1e-10f);
    pcr = rec[tid][1]; pcg = rec[tid][2]; pcb = rec[tid][3];
    pnx = rec[tid][4]; pny = rec[tid][5]; pnz = rec[tid][6];
    pdt = tn + span * (((float)tid + 0.5f) * (1.0f / (float)S_PER));
    scanb[tid] = l;
  }
  __syncthreads();
  #pragma unroll
  for (int st = 1; st < S_PER; st <<= 1) {
    float v = 0.0f;
    if (tid < S_PER && tid >= st) v = scanb[tid - st];
    __syncthreads();
    if (tid < S_PER) scanb[tid] += v;
    __syncthreads();
  }
  if (tid < S_PER) {
    float T = expf(scanb[tid] - l);   // exclusive prefix -> transmittance
    float w = a * T;
    rec[tid][0] = w;
    rec[tid][1] = w * pcr; rec[tid][2] = w * pcg; rec[tid][3] = w * pcb;
    rec[tid][4] = w * pnx; rec[tid][5] = w * pny; rec[tid][6] = w * pnz;
    scanb[tid] = w * pdt;
  }
  __syncthreads();
  #pragma unroll
  for (int off = 48; off >= 3; off >>= 1) {   // 48,24,12,6,3
    if (tid < off) {
      #pragma unroll
      for (int k = 0; k < 7; k++) rec[tid][k] += rec[tid + off][k];
      scanb[tid] += scanb[tid + off];
    }
    __syncthreads();
  }
  if (tid == 0) {
    float R[7];
    #pragma unroll
    for (int k = 0; k < 7; k++) R[k] = rec[0][k] + rec[1][k] + rec[2][k];
    float dsum = scanb[0] + scanb[1] + scanb[2];
    float wsum = R[0];
    float nl = sqrtf(R[4] * R[4] + R[5] * R[5] + R[6] * R[6]) + 1e-8f;
    float inl = 1.0f / nl;
    float nrm3[3] = {R[4], R[5], R[6]};
    float rgb3[3] = {R[1], R[2], R[3]};
    #pragma unroll
    for (int c = 0; c < 3; c++) {
      float n = (nrm3[c] * inl + 1.0f) * 0.5f * wsum;
      stout<BF16>(out, (size_t)(c * 4096 + ray), rgb3[c] + 1.0f - wsum);
      stout<BF16>(out, (size_t)(20480 + c * 4096 + ray), n);
    }
    stout<BF16>(out, (size_t)(12288 + ray), dsum);
    stout<BF16>(out, (size_t)(16384 + ray), wsum);
  }
}

extern "C" void kernel_launch(void* const* d_in, const int* in_sizes, int n_in,
                              void* d_out, int out_size, void* d_ws, size_t ws_size,
                              hipStream_t stream) {
  const void* planes = d_in[0];
  const void* ro     = d_in[1];
  const void* rd     = d_in[2];
  const void* W1     = d_in[3];
  const void* b1     = d_in[4];
  const void* W2     = d_in[5];
  const void* b2     = d_in[6];
  float* ws = (float*)d_ws;

  detect_kernel<<<1, 64, 0, stream>>>(rd, ws);
  prep_kernel<false><<<128, 256, 0, stream>>>(W1, b1, W2, b2, ws);
  prep_kernel<true ><<<128, 256, 0, stream>>>(W1, b1, W2, b2, ws);
  transpose_kernel<false><<<240, 256, 0, stream>>>(planes, ws);
  transpose_kernel<true ><<<240, 256, 0, stream>>>(planes, ws);
  fused_kernel<false><<<NUM_RAYS, 256, 0, stream>>>(ro, rd, ws, d_out);
  fused_kernel<true ><<<NUM_RAYS, 256, 0, stream>>>(ro, rd, ws, d_out);
}

// Round 9
// 317.060 us; speedup vs baseline: 7.2948x; 1.0506x over previous
//
#include <hip/hip_runtime.h>
#include <hip/hip_bf16.h>

#define NUM_RAYS 4096
#define S_PER 96
#define NPTS (NUM_RAYS * S_PER)
#define CCH 80
#define HID 64

// ws layout (byte offsets)
#define WSB_FLAG   0         // int
#define WSB_W2     256       // 256 f32 (64x4)
#define WSB_B1     1536      // 64 f32
#define WSB_B2     1856      // 4 f32
#define WSB_W1S    4096      // 15360 bf16 shorts, compact MFMA B-frag order (30720 B)
#define WSB_PT     40960     // 983040 bf16: planesT [p][y*64+x][80]

// w1s compact layout (shorts): plane p base = p*5120;
//  ccl 0,1: + ccl*2048 + (nb*64+lane)*8 + j        (k = 8*quad+j, ch = ccl*32+k)
//  ccl 2:   + 4096     + (nb*32+(lane&31))*8 + j   (quads 0,1 only; ch = 64+8*quad+j)

// d_out layout (elements of output dtype):
// [0) comp_rgb 3*4096 | [12288) depth 4096 | [16384) opacity 4096
// [20480) comp_normal 3*4096 | [32768) sdf_grad 393216*3

typedef __attribute__((ext_vector_type(8))) short short8;
typedef __attribute__((ext_vector_type(4))) float f32x4;
typedef __attribute__((ext_vector_type(2))) float f32x2;

__device__ __forceinline__ float bf2f(__hip_bfloat16 v) { return __bfloat162float(v); }

__device__ __forceinline__ short f2bs(float f) {
  __hip_bfloat16 h = __float2bfloat16(f);
  short s; __builtin_memcpy(&s, &h, 2); return s;
}

template <bool BF16>
__device__ __forceinline__ float ldin(const void* p, size_t i) {
  if (BF16) return bf2f(((const __hip_bfloat16*)p)[i]);
  else      return ((const float*)p)[i];
}
template <bool BF16>
__device__ __forceinline__ void stout(void* p, size_t i, float v) {
  if (BF16) ((__hip_bfloat16*)p)[i] = __float2bfloat16(v);
  else      ((float*)p)[i] = v;
}

// unpack bf16x2 dword -> f32x2 (lo, hi)
__device__ __forceinline__ f32x2 unpk2(unsigned u) {
  f32x2 r;
  r.x = __uint_as_float(u << 16);
  r.y = __uint_as_float(u & 0xffff0000u);
  return r;
}

// pack two f32 -> packed bf16x2 (lo in low16, hi in high16)
__device__ __forceinline__ unsigned pack_bf16(float lo, float hi) {
#if __has_builtin(__builtin_amdgcn_cvt_pk_bf16_f32)
  typedef __attribute__((ext_vector_type(2))) __bf16 b2t;
  b2t r = __builtin_amdgcn_cvt_pk_bf16_f32(lo, hi);
  unsigned u; __builtin_memcpy(&u, &r, 4); return u;
#else
  unsigned ul = __float_as_uint(lo) + 0x8000u;   // round-half-up
  unsigned uh = __float_as_uint(hi) + 0x8000u;
  return __builtin_amdgcn_perm(uh, ul, 0x07060302);
#endif
}

// Detect input dtype: bf16 ray-direction norms are ~1; f32 misread as bf16 is garbage.
__global__ void detect_kernel(const void* __restrict__ rdv, float* __restrict__ ws) {
  int lane = threadIdx.x;  // 64 threads
  const __hip_bfloat16* p = (const __hip_bfloat16*)rdv;
  float x = bf2f(p[lane * 3 + 0]);
  float y = bf2f(p[lane * 3 + 1]);
  float z = bf2f(p[lane * 3 + 2]);
  float n2 = x * x + y * y + z * z;
  bool ok = (n2 > 0.95f) && (n2 < 1.05f);
  unsigned long long m = __ballot(ok);
  if (lane == 0) *((int*)((char*)ws + WSB_FLAG)) = (m == ~0ull) ? 1 : 0;
}

template <bool BF16>
__global__ void prep_kernel(const void* __restrict__ W1,
                            const void* __restrict__ b1,
                            const void* __restrict__ W2,
                            const void* __restrict__ b2,
                            float* __restrict__ ws) {
  if ((*((const int*)((char*)ws + WSB_FLAG)) != 0) != BF16) return;
  int tid = blockIdx.x * blockDim.x + threadIdx.x;
  unsigned short* w1sw = (unsigned short*)((char*)ws + WSB_W1S);
  if (tid < 15360) {
    int p = tid / 5120;
    int r = tid - p * 5120;
    int ch, n;
    if (r < 4096) {
      int ccl  = r >> 11;
      int r2   = r & 2047;
      int j    = r2 & 7;
      int lane = (r2 >> 3) & 63;
      int nb   = r2 >> 9;
      ch = ccl * 32 + 8 * (lane >> 4) + j;
      n  = nb * 16 + (lane & 15);
    } else {
      int r2   = r - 4096;
      int j    = r2 & 7;
      int l31  = (r2 >> 3) & 31;
      int nb   = r2 >> 8;
      ch = 64 + 8 * (l31 >> 4) + j;
      n  = nb * 16 + (l31 & 15);
    }
    w1sw[tid] = (unsigned short)f2bs(ldin<BF16>(W1, (size_t)(p * 80 + ch) * 64 + n));
  }
  float* w2f = (float*)((char*)ws + WSB_W2);
  float* b1f = (float*)((char*)ws + WSB_B1);
  float* b2f = (float*)((char*)ws + WSB_B2);
  if (tid < 256) w2f[tid] = ldin<BF16>(W2, tid);
  if (tid < 64)  b1f[tid] = ldin<BF16>(b1, tid);
  if (tid < 4)   b2f[tid] = ldin<BF16>(b2, tid);
}

// planes[p][c][y][x] -> planesT[p][y*64+x][80] (bf16, channel-last).
// grid: 3 planes x 5 ctiles x 16 textiles = 240 blocks, 256 threads.
template <bool BF16>
__global__ void transpose_kernel(const void* __restrict__ planes, float* __restrict__ ws) {
  if ((*((const int*)((char*)ws + WSB_FLAG)) != 0) != BF16) return;
  int b  = blockIdx.x;
  int tt = b & 15;
  int ct = (b >> 4) % 5;
  int p  = b / 80;
  int tex = tt * 256 + threadIdx.x;
  unsigned u[8];
  #pragma unroll
  for (int i = 0; i < 8; i++) {
    int c0 = ct * 16 + 2 * i;
    float v0 = ldin<BF16>(planes, ((size_t)(p * 80 + c0) * 4096) + tex);
    float v1 = ldin<BF16>(planes, ((size_t)(p * 80 + c0 + 1) * 4096) + tex);
    unsigned s0 = (unsigned short)f2bs(v0);
    unsigned s1 = (unsigned short)f2bs(v1);
    u[i] = s0 | (s1 << 16);
  }
  unsigned short* ptb = (unsigned short*)((char*)ws + WSB_PT);
  uint4* dst = (uint4*)(ptb + ((size_t)(p * 4096 + tex) * 80 + ct * 16));
  dst[0] = make_uint4(u[0], u[1], u[2], u[3]);
  dst[1] = make_uint4(u[4], u[5], u[6], u[7]);
}

struct TapInfo {
  float w00, w10, w01, w11;
  int o00, o10, o01, o11;   // texel indices (y*64+x)
};
__device__ __forceinline__ TapInfo tap_setup(float u, float v) {
  TapInfo t;
  float fx = u * 32.0f + 31.5f;
  float fy = v * 32.0f + 31.5f;
  float flx = floorf(fx), fly = floorf(fy);
  int x0 = (int)flx, y0 = (int)fly;
  float wx = fx - flx, wy = fy - fly;
  int x1 = x0 + 1, y1 = y0 + 1;
  bool vx0 = (x0 >= 0) && (x0 < 64);
  bool vx1 = (x1 >= 0) && (x1 < 64);
  bool vy0 = (y0 >= 0) && (y0 < 64);
  bool vy1 = (y1 >= 0) && (y1 < 64);
  int cx0 = min(max(x0, 0), 63), cx1 = min(max(x1, 0), 63);
  int cy0 = min(max(y0, 0), 63), cy1 = min(max(y1, 0), 63);
  t.w00 = (1.0f - wx) * (1.0f - wy) * ((vx0 && vy0) ? 1.0f : 0.0f);
  t.w10 = wx * (1.0f - wy)          * ((vx1 && vy0) ? 1.0f : 0.0f);
  t.w01 = (1.0f - wx) * wy          * ((vx0 && vy1) ? 1.0f : 0.0f);
  t.w11 = wx * wy                   * ((vx1 && vy1) ? 1.0f : 0.0f);
  t.o00 = cy0 * 64 + cx0; t.o10 = cy0 * 64 + cx1;
  t.o01 = cy1 * 64 + cx0; t.o11 = cy1 * 64 + cx1;
  return t;
}

// Block = 1 ray: 4 waves x 6 iterations x (4 samples x 4 decodes = 16 MFMA rows).
// Per-plane K loop (one TapInfo live); compact W1 LDS (30 KB, no waste) ->
// total LDS 33.8 KB -> 4 blocks/CU. Packed-f32 (v_pk_fma_f32) bilinear.
template <bool BF16>
__global__ __launch_bounds__(256) void fused_kernel(
    const void* __restrict__ ro,
    const void* __restrict__ rd,
    const float* __restrict__ ws,
    void* __restrict__ out) {
  if ((*((const int*)((const char*)ws + WSB_FLAG)) != 0) != BF16) return;

  __shared__ __align__(16) unsigned short w1s[15360];  // 30 KB compact
  __shared__ float rec[S_PER][7];   // alpha, r,g,b, nx,ny,nz
  __shared__ float scanb[S_PER];

  const unsigned short* ptb = (const unsigned short*)((const char*)ws + WSB_PT);
  const float* w2f = (const float*)((const char*)ws + WSB_W2);
  const float* b1f = (const float*)((const char*)ws + WSB_B1);
  const float* b2f = (const float*)((const char*)ws + WSB_B2);

  int tid = threadIdx.x;
  int wave = tid >> 6;
  int lane = tid & 63;
  int lane15 = lane & 15;
  int quad = lane >> 4;
  int ray = blockIdx.x;

  // stage compact W1 (30720 B = 1920 uint4) into LDS
  {
    const uint4* src = (const uint4*)((const char*)ws + WSB_W1S);
    uint4* dst = (uint4*)w1s;
    #pragma unroll
    for (int t = 0; t < 8; t++) {
      int idx = tid + 256 * t;
      if (idx < 1920) dst[idx] = src[idx];
    }
  }

  // ray data (uniform across block)
  float ox = ldin<BF16>(ro, (size_t)ray*3+0), oy = ldin<BF16>(ro, (size_t)ray*3+1), oz = ldin<BF16>(ro, (size_t)ray*3+2);
  float dx = ldin<BF16>(rd, (size_t)ray*3+0), dy = ldin<BF16>(rd, (size_t)ray*3+1), dz = ldin<BF16>(rd, (size_t)ray*3+2);
  float o3[3] = {ox, oy, oz}, d3[3] = {dx, dy, dz};
  float tmin = -1e30f, tmax = 1e30f;
  #pragma unroll
  for (int k = 0; k < 3; k++) {
    float sd = (fabsf(d3[k]) < 1e-9f) ? 1e-9f : d3[k];
    float ta = (-0.6f - o3[k]) / sd;
    float tb = ( 0.6f - o3[k]) / sd;
    tmin = fmaxf(tmin, fminf(ta, tb));
    tmax = fminf(tmax, fmaxf(ta, tb));
  }
  float tn = fmaxf(tmin, 0.0f);
  float span = fmaxf(tmax - tn, 0.0f);
  float delta = span * (1.0f / (float)S_PER);
  float b2_0 = b2f[0], b2_1 = b2f[1], b2_2 = b2f[2], b2_3 = b2f[3];
  // per-lane weights in VGPRs
  float b1x[4];
  float4 w2r[4];
  #pragma unroll
  for (int nb = 0; nb < 4; nb++) {
    b1x[nb] = b1f[nb * 16 + lane15];
    w2r[nb] = *(const float4*)(w2f + (nb * 16 + lane15) * 4);
  }

  __syncthreads();

  #pragma unroll 1
  for (int it = 0; it < 6; it++) {
    int sbase = it * 16 + wave * 4;

    // ---- feature stage: this lane feeds A-row m = lane15 (sample sF, decode d)
    int sF = sbase + (lane15 >> 2);
    int d  = lane15 & 3;
    float depF = tn + span * (((float)sF + 0.5f) * (1.0f / (float)S_PER));
    float px = ox + depF * dx, py = oy + depF * dy, pz = oz + depF * dz;
    if (d == 1) px += 0.01f;
    if (d == 2) py += 0.01f;
    if (d == 3) pz += 0.01f;
    if (d > 0) {
      px = fminf(fmaxf(px, -0.6f), 0.6f);
      py = fminf(fmaxf(py, -0.6f), 0.6f);
      pz = fminf(fmaxf(pz, -0.6f), 0.6f);
    }
    const float inv = 1.0f / 0.6f;
    float ux = px * inv, uy = py * inv, uz = pz * inv;

    f32x4 acc[4];
    #pragma unroll
    for (int nb = 0; nb < 4; nb++) acc[nb] = (f32x4){0.f, 0.f, 0.f, 0.f};

    #pragma unroll 1
    for (int p = 0; p < 3; p++) {
      float u = (p == 2) ? uy : ux;
      float v = (p == 0) ? uy : uz;
      TapInfo t = tap_setup(u, v);
      // hoisted per-plane corner pointers incl. this lane's k-offset (8*quad ch)
      const unsigned short* c00p = ptb + (size_t)p * 327680 + t.o00 * 80 + 8 * quad;
      const unsigned short* c10p = ptb + (size_t)p * 327680 + t.o10 * 80 + 8 * quad;
      const unsigned short* c01p = ptb + (size_t)p * 327680 + t.o01 * 80 + 8 * quad;
      const unsigned short* c11p = ptb + (size_t)p * 327680 + t.o11 * 80 + 8 * quad;
      f32x2 wv00 = {t.w00, t.w00}, wv10 = {t.w10, t.w10};
      f32x2 wv01 = {t.w01, t.w01}, wv11 = {t.w11, t.w11};
      const unsigned short* w1p = w1s + p * 5120;
      #pragma unroll
      for (int ccl = 0; ccl < 3; ccl++) {
        int4 afi = {0, 0, 0, 0};
        if (ccl < 2 || quad < 2) {   // live lanes
          uint4 q00 = *(const uint4*)(c00p + 32 * ccl);
          uint4 q10 = *(const uint4*)(c10p + 32 * ccl);
          uint4 q01 = *(const uint4*)(c01p + 32 * ccl);
          uint4 q11 = *(const uint4*)(c11p + 32 * ccl);
          unsigned u00[4] = {q00.x, q00.y, q00.z, q00.w};
          unsigned u10[4] = {q10.x, q10.y, q10.z, q10.w};
          unsigned u01[4] = {q01.x, q01.y, q01.z, q01.w};
          unsigned u11[4] = {q11.x, q11.y, q11.z, q11.w};
          int ae[4];
          #pragma unroll
          for (int q = 0; q < 4; q++) {
            f32x2 f = unpk2(u00[q]) * wv00;               // v_pk_mul_f32
            f = __builtin_elementwise_fma(unpk2(u10[q]), wv10, f);
            f = __builtin_elementwise_fma(unpk2(u01[q]), wv01, f);
            f = __builtin_elementwise_fma(unpk2(u11[q]), wv11, f);
            ae[q] = (int)pack_bf16(f.x, f.y);
          }
          afi.x = ae[0]; afi.y = ae[1]; afi.z = ae[2]; afi.w = ae[3];
        }
        short8 afr;
        __builtin_memcpy(&afr, &afi, 16);
        #pragma unroll
        for (int nb = 0; nb < 4; nb++) {
          // compact B-frag: ccl 0,1 full; ccl 2 half (quads 2,3 alias — A is 0 there)
          int boff = (ccl < 2) ? (ccl * 2048 + (nb * 64 + lane) * 8)
                               : (4096 + (nb * 32 + (lane & 31)) * 8);
          short8 bfr = *(const short8*)(w1p + boff);
          acc[nb] = __builtin_amdgcn_mfma_f32_16x16x32_bf16(afr, bfr, acc[nb], 0, 0, 0);
        }
      }
    }

    // ---- layer 2: lane holds h[m=quad*4+reg][n=nb*16+lane15]; d == reg.
    float vals[7];
    #pragma unroll
    for (int k = 0; k < 7; k++) vals[k] = 0.0f;
    #pragma unroll
    for (int nb = 0; nb < 4; nb++) {
      float hr0 = fmaxf(acc[nb][0] + b1x[nb], 0.0f);
      vals[0] = fmaf(hr0, w2r[nb].x, vals[0]);
      vals[4] = fmaf(hr0, w2r[nb].y, vals[4]);
      vals[5] = fmaf(hr0, w2r[nb].z, vals[5]);
      vals[6] = fmaf(hr0, w2r[nb].w, vals[6]);
      float hr1 = fmaxf(acc[nb][1] + b1x[nb], 0.0f);
      float hr2 = fmaxf(acc[nb][2] + b1x[nb], 0.0f);
      float hr3 = fmaxf(acc[nb][3] + b1x[nb], 0.0f);
      vals[1] = fmaf(hr1, w2r[nb].x, vals[1]);
      vals[2] = fmaf(hr2, w2r[nb].x, vals[2]);
      vals[3] = fmaf(hr3, w2r[nb].x, vals[3]);
    }
    #pragma unroll
    for (int mask = 1; mask < 16; mask <<= 1) {
      #pragma unroll
      for (int k = 0; k < 7; k++) vals[k] += __shfl_xor(vals[k], mask, 64);
    }

    // ---- epilogue: this lane's quad owns sample sE
    int sE = sbase + quad;
    float sdf0 = vals[0] + b2_0;
    float g0 = (vals[1] - vals[0]) * 100.0f;
    float g1 = (vals[2] - vals[0]) * 100.0f;
    float g2 = (vals[3] - vals[0]) * 100.0f;
    float cr = 1.0f / (1.0f + expf(-(vals[4] + b2_1))) * 1.002f - 0.001f;
    float cg = 1.0f / (1.0f + expf(-(vals[5] + b2_2))) * 1.002f - 0.001f;
    float cb = 1.0f / (1.0f + expf(-(vals[6] + b2_3))) * 1.002f - 0.001f;
    float depE = tn + span * (((float)sE + 0.5f) * (1.0f / (float)S_PER));
    float ex = ox + depE * dx, ey = oy + depE * dy, ez = oz + depE * dz;
    float pn = sqrtf(ex * ex + ey * ey + ez * ez);
    float shifted = sdf0 + pn - 0.5f;
    float xarg = -shifted * 80.0f;
    float sigma = (xarg > 20.0f) ? xarg : log1pf(expf(xarg));
    float alpha = 1.0f - expf(-sigma * delta);
    float gl = sqrtf(g0 * g0 + g1 * g1 + g2 * g2) + 1e-8f;
    float igl = 1.0f / gl;

    if (lane15 == 0) {
      rec[sE][0] = alpha;
      rec[sE][1] = cr; rec[sE][2] = cg; rec[sE][3] = cb;
      rec[sE][4] = g0 * igl; rec[sE][5] = g1 * igl; rec[sE][6] = g2 * igl;
      size_t gid = (size_t)ray * S_PER + sE;
      stout<BF16>(out, (size_t)32768 + gid * 3 + 0, g0);
      stout<BF16>(out, (size_t)32768 + gid * 3 + 1, g1);
      stout<BF16>(out, (size_t)32768 + gid * 3 + 2, g2);
    }
  }

  __syncthreads();

  // ---- parallel composite: log-space scan for transmittance, tree reduction
  float a = 0.f, l = 0.f, pcr = 0.f, pcg = 0.f, pcb = 0.f, pnx = 0.f, pny = 0.f, pnz = 0.f, pdt = 0.f;
  if (tid < S_PER) {
    a = rec[tid][0];
    l = logf(1.0f - a + 1e-10f);
    pcr = rec[tid][1]; pcg = rec[tid][2]; pcb = rec[tid][3];
    pnx = rec[tid][4]; pny = rec[tid][5]; pnz = rec[tid][6];
    pdt = tn + span * (((float)tid + 0.5f) * (1.0f / (float)S_PER));
    scanb[tid] = l;
  }
  __syncthreads();
  #pragma unroll
  for (int st = 1; st < S_PER; st <<= 1) {
    float v = 0.0f;
    if (tid < S_PER && tid >= st) v = scanb[tid - st];
    __syncthreads();
    if (tid < S_PER) scanb[tid] += v;
    __syncthreads();
  }
  if (tid < S_PER) {
    float T = expf(scanb[tid] - l);   // exclusive prefix -> transmittance
    float w = a * T;
    rec[tid][0] = w;
    rec[tid][1] = w * pcr; rec[tid][2] = w * pcg; rec[tid][3] = w * pcb;
    rec[tid][4] = w * pnx; rec[tid][5] = w * pny; rec[tid][6] = w * pnz;
    scanb[tid] = w * pdt;
  }
  __syncthreads();
  #pragma unroll
  for (int off = 48; off >= 3; off >>= 1) {   // 48,24,12,6,3
    if (tid < off) {
      #pragma unroll
      for (int k = 0; k < 7; k++) rec[tid][k] += rec[tid + off][k];
      scanb[tid] += scanb[tid + off];
    }
    __syncthreads();
  }
  if (tid == 0) {
    float R[7];
    #pragma unroll
    for (int k = 0; k < 7; k++) R[k] = rec[0][k] + rec[1][k] + rec[2][k];
    float dsum = scanb[0] + scanb[1] + scanb[2];
    float wsum = R[0];
    float nl = sqrtf(R[4] * R[4] + R[5] * R[5] + R[6] * R[6]) + 1e-8f;
    float inl = 1.0f / nl;
    float nrm3[3] = {R[4], R[5], R[6]};
    float rgb3[3] = {R[1], R[2], R[3]};
    #pragma unroll
    for (int c = 0; c < 3; c++) {
      float n = (nrm3[c] * inl + 1.0f) * 0.5f * wsum;
      stout<BF16>(out, (size_t)(c * 4096 + ray), rgb3[c] + 1.0f - wsum);
      stout<BF16>(out, (size_t)(20480 + c * 4096 + ray), n);
    }
    stout<BF16>(out, (size_t)(12288 + ray), dsum);
    stout<BF16>(out, (size_t)(16384 + ray), wsum);
  }
}

extern "C" void kernel_launch(void* const* d_in, const int* in_sizes, int n_in,
                              void* d_out, int out_size, void* d_ws, size_t ws_size,
                              hipStream_t stream) {
  const void* planes = d_in[0];
  const void* ro     = d_in[1];
  const void* rd     = d_in[2];
  const void* W1     = d_in[3];
  const void* b1     = d_in[4];
  const void* W2     = d_in[5];
  const void* b2     = d_in[6];
  float* ws = (float*)d_ws;

  detect_kernel<<<1, 64, 0, stream>>>(rd, ws);
  prep_kernel<false><<<64, 256, 0, stream>>>(W1, b1, W2, b2, ws);
  prep_kernel<true ><<<64, 256, 0, stream>>>(W1, b1, W2, b2, ws);
  transpose_kernel<false><<<240, 256, 0, stream>>>(planes, ws);
  transpose_kernel<true ><<<240, 256, 0, stream>>>(planes, ws);
  fused_kernel<false><<<NUM_RAYS, 256, 0, stream>>>(ro, rd, ws, d_out);
  fused_kernel<true ><<<NUM_RAYS, 256, 0, stream>>>(ro, rd, ws, d_out);
}